// Round 1
// baseline (12687.762 us; speedup 1.0000x reference)
//
#include <hip/hip_runtime.h>
#include <hip/hip_bf16.h>
#include <math.h>

#define NNODES 32768
#define NEDGES 524288
#define CCH 128
#define NLAYERS 3
#define NHEADS 4
#define HDIM 32
#define NB_GRAPH 64
#define SNODES 512
#define INDIM 80
#define HIDDEN 256
#define BNEPS 1e-5f

__device__ __forceinline__ float gelu_f(float x) {
    return 0.5f * x * (1.0f + erff(x * 0.70710678118654752f));
}

// ---------------- utility kernels ----------------
__global__ void k_fill(float* p, float v, int n) {
    int i = blockIdx.x * blockDim.x + threadIdx.x;
    if (i < n) p[i] = v;
}

__global__ void k_deg_scatter(const int* __restrict__ dst, float* deg) {
    int e = blockIdx.x * blockDim.x + threadIdx.x;
    if (e < NEDGES) atomicAdd(&deg[dst[e]], 1.0f);
}

__global__ void k_rsqrt(float* p, int n) {
    int i = blockIdx.x * blockDim.x + threadIdx.x;
    if (i < n) p[i] = rsqrtf(p[i]);
}

// concat [x | pe] -> out [N, 80], processed as float4 (20 per row)
__global__ void k_concat(const float* __restrict__ x, const float* __restrict__ pe,
                         float* __restrict__ out) {
    int gid = blockIdx.x * blockDim.x + threadIdx.x;
    if (gid >= NNODES * 20) return;
    int n = gid / 20, q = gid % 20;
    float4 v;
    if (q < 16) v = ((const float4*)x)[(size_t)n * 16 + q];
    else        v = ((const float4*)pe)[(size_t)n * 4 + (q - 16)];
    ((float4*)out)[gid] = v;
}

// ---------------- GEMM: C[M,N] = act(A[M,K] @ B + bias) ----------------
// TRANSB=false: B is [K,N] row-major.  TRANSB=true: B is [N,K] row-major (i.e. A @ B^T).
// ACT: 0 = none, 1 = relu
template<int ACT, bool TRANSB>
__global__ __launch_bounds__(256) void k_gemm64(
        const float* __restrict__ A, const float* __restrict__ B,
        const float* __restrict__ bias, float* __restrict__ C,
        int M, int N, int K) {
    __shared__ float As[16][68];
    __shared__ float Bs[16][68];
    const int tid = threadIdx.x;
    const int bm = blockIdx.y * 64, bn = blockIdx.x * 64;
    const int tx = tid & 15, ty = tid >> 4;
    float acc[4][4] = {};

    for (int k0 = 0; k0 < K; k0 += 16) {
        {
            int m = tid >> 2, k = (tid & 3) * 4;
            float4 v = *(const float4*)(A + (size_t)(bm + m) * K + k0 + k);
            As[k][m] = v.x; As[k + 1][m] = v.y; As[k + 2][m] = v.z; As[k + 3][m] = v.w;
        }
        if (!TRANSB) {
            int k = tid >> 4, n = (tid & 15) * 4;
            float4 v = *(const float4*)(B + (size_t)(k0 + k) * N + bn + n);
            Bs[k][n] = v.x; Bs[k][n + 1] = v.y; Bs[k][n + 2] = v.z; Bs[k][n + 3] = v.w;
        } else {
            int n = tid >> 2, k = (tid & 3) * 4;
            float4 v = *(const float4*)(B + (size_t)(bn + n) * K + k0 + k);
            Bs[k][n] = v.x; Bs[k + 1][n] = v.y; Bs[k + 2][n] = v.z; Bs[k + 3][n] = v.w;
        }
        __syncthreads();
        #pragma unroll
        for (int k = 0; k < 16; k++) {
            float4 av = *(const float4*)&As[k][ty * 4];
            float4 bv = *(const float4*)&Bs[k][tx * 4];
            float a0[4] = {av.x, av.y, av.z, av.w};
            float b0[4] = {bv.x, bv.y, bv.z, bv.w};
            #pragma unroll
            for (int i = 0; i < 4; i++)
                #pragma unroll
                for (int j = 0; j < 4; j++)
                    acc[i][j] = fmaf(a0[i], b0[j], acc[i][j]);
        }
        __syncthreads();
    }

    float bv[4];
    #pragma unroll
    for (int j = 0; j < 4; j++) bv[j] = bias ? bias[bn + tx * 4 + j] : 0.0f;
    #pragma unroll
    for (int i = 0; i < 4; i++) {
        int row = bm + ty * 4 + i;
        float4 o;
        float r[4];
        #pragma unroll
        for (int j = 0; j < 4; j++) {
            float v = acc[i][j] + bv[j];
            if (ACT == 1) v = fmaxf(v, 0.0f);
            r[j] = v;
        }
        o.x = r[0]; o.y = r[1]; o.z = r[2]; o.w = r[3];
        *(float4*)(C + (size_t)row * N + bn + tx * 4) = o;
    }
}

// ---------------- GCN ----------------
// loc[i,c] = xw[i,c]*dinv[i]^2 + bias[c]   (self-loop + bias)
__global__ void k_locinit(const float* __restrict__ xw, const float* __restrict__ dinv,
                          const float* __restrict__ bias, float* __restrict__ loc) {
    int gid = blockIdx.x * blockDim.x + threadIdx.x;
    if (gid >= NNODES * 32) return;
    int n = gid >> 5, c4 = gid & 31;
    float dv = dinv[n];
    float cf = dv * dv;
    float4 v = ((const float4*)xw)[gid];
    float4 bvv = ((const float4*)bias)[c4];
    float4 o;
    o.x = fmaf(v.x, cf, bvv.x); o.y = fmaf(v.y, cf, bvv.y);
    o.z = fmaf(v.z, cf, bvv.z); o.w = fmaf(v.w, cf, bvv.w);
    ((float4*)loc)[gid] = o;
}

// loc[dst] += xw[src] * (dinv[src]*dinv[dst]), 4 threads per edge (32 channels each)
__global__ void k_gcn_scatter(const int* __restrict__ src, const int* __restrict__ dst,
                              const float* __restrict__ dinv, const float* __restrict__ xw,
                              float* __restrict__ loc) {
    int gid = blockIdx.x * blockDim.x + threadIdx.x;
    int e = gid >> 2;
    if (e >= NEDGES) return;
    int q = gid & 3;
    int s = src[e], d = dst[e];
    float coef = dinv[s] * dinv[d];
    const float4* xp = (const float4*)(xw + (size_t)s * CCH + q * 32);
    float* lp = loc + (size_t)d * CCH + q * 32;
    #pragma unroll
    for (int i = 0; i < 8; i++) {
        float4 v = xp[i];
        atomicAdd(lp + i * 4 + 0, v.x * coef);
        atomicAdd(lp + i * 4 + 1, v.y * coef);
        atomicAdd(lp + i * 4 + 2, v.z * coef);
        atomicAdd(lp + i * 4 + 3, v.w * coef);
    }
}

// ---------------- BatchNorm ----------------
// partials over (a+b): part[blk][0][c]=sum, part[blk][1][c]=sumsq ; 128 blocks x 256 rows
__global__ __launch_bounds__(256) void k_bn_stats(const float* __restrict__ a,
                                                  const float* __restrict__ b,
                                                  float* __restrict__ part) {
    __shared__ float s1[256], s2[256];
    int t = threadIdx.x, blk = blockIdx.x;
    int c = t & 127, half = t >> 7;
    float sum = 0.f, sq = 0.f;
    for (int i = 0; i < 128; i++) {
        size_t r = (size_t)blk * 256 + half + 2 * i;
        float v = a[r * CCH + c] + b[r * CCH + c];
        sum += v;
        sq = fmaf(v, v, sq);
    }
    s1[t] = sum; s2[t] = sq;
    __syncthreads();
    if (t < 128) {
        part[blk * 256 + t]       = s1[t] + s1[t + 128];
        part[blk * 256 + 128 + t] = s2[t] + s2[t + 128];
    }
}

__global__ void k_bn_finalize(const float* __restrict__ part, const float* __restrict__ g,
                              const float* __restrict__ be, float* __restrict__ sc,
                              float* __restrict__ sh) {
    int c = threadIdx.x;  // 128 threads
    float s = 0.f, sq = 0.f;
    for (int bk = 0; bk < 128; bk++) {
        s  += part[bk * 256 + c];
        sq += part[bk * 256 + 128 + c];
    }
    float mu = s / (float)NNODES;
    float var = sq / (float)NNODES - mu * mu;
    float rs = rsqrtf(var + BNEPS);
    float gg = g[c] * rs;
    sc[c] = gg;
    sh[c] = be[c] - mu * gg;
}

// out = act((a+b)*sc + sh) ; ACT: 0 none, 2 gelu
template<int ACT>
__global__ void k_bn_apply(const float* __restrict__ a, const float* __restrict__ b,
                           const float* __restrict__ sc, const float* __restrict__ sh,
                           float* __restrict__ out) {
    int gid = blockIdx.x * blockDim.x + threadIdx.x;
    if (gid >= NNODES * 32) return;
    int c = (gid & 31) * 4;
    float4 av = ((const float4*)a)[gid];
    float4 bv = ((const float4*)b)[gid];
    float r[4];
    float xs[4] = {av.x + bv.x, av.y + bv.y, av.z + bv.z, av.w + bv.w};
    #pragma unroll
    for (int j = 0; j < 4; j++) {
        float v = fmaf(xs[j], sc[c + j], sh[c + j]);
        if (ACT == 2) v = gelu_f(v);
        r[j] = v;
    }
    float4 o = {r[0], r[1], r[2], r[3]};
    ((float4*)out)[gid] = o;
}

__global__ void k_add(float* __restrict__ a, const float* __restrict__ b) {
    int gid = blockIdx.x * blockDim.x + threadIdx.x;
    if (gid >= NNODES * 32) return;
    float4 av = ((float4*)a)[gid];
    float4 bv = ((const float4*)b)[gid];
    av.x += bv.x; av.y += bv.y; av.z += bv.z; av.w += bv.w;
    ((float4*)a)[gid] = av;
}

// ---------------- attention ----------------
// one block per (graph, head); thread t owns query row t; two-pass online softmax
__global__ __launch_bounds__(512) void k_attn(const float* __restrict__ qkv,
                                              float* __restrict__ ao) {
    __shared__ float KT[64][32];
    __shared__ float VT[64][32];
    const int bh = blockIdx.x;
    const int b = bh >> 2, hh = bh & 3;
    const int t = threadIdx.x;
    const float scale = 0.17677669529663689f;  // 1/sqrt(32)

    const float* qp = qkv + ((size_t)(b * SNODES + t)) * 384 + hh * HDIM;
    float q[32];
    #pragma unroll
    for (int i = 0; i < 8; i++) {
        float4 v = ((const float4*)qp)[i];
        q[i * 4 + 0] = v.x * scale; q[i * 4 + 1] = v.y * scale;
        q[i * 4 + 2] = v.z * scale; q[i * 4 + 3] = v.w * scale;
    }

    const int lrow = t >> 3, lc4 = t & 7;
    float m = -INFINITY, l = 0.f;

    for (int j0 = 0; j0 < SNODES; j0 += 64) {
        __syncthreads();
        ((float4*)KT[lrow])[lc4] = *(const float4*)(qkv +
            ((size_t)(b * SNODES + j0 + lrow)) * 384 + CCH + hh * HDIM + lc4 * 4);
        __syncthreads();
        for (int j = 0; j < 64; j++) {
            float s = 0.f;
            #pragma unroll
            for (int i = 0; i < 32; i++) s = fmaf(q[i], KT[j][i], s);
            float mn = fmaxf(m, s);
            l = l * __expf(m - mn) + __expf(s - mn);
            m = mn;
        }
    }

    float acc[32];
    #pragma unroll
    for (int i = 0; i < 32; i++) acc[i] = 0.f;

    for (int j0 = 0; j0 < SNODES; j0 += 64) {
        __syncthreads();
        ((float4*)KT[lrow])[lc4] = *(const float4*)(qkv +
            ((size_t)(b * SNODES + j0 + lrow)) * 384 + CCH + hh * HDIM + lc4 * 4);
        ((float4*)VT[lrow])[lc4] = *(const float4*)(qkv +
            ((size_t)(b * SNODES + j0 + lrow)) * 384 + 2 * CCH + hh * HDIM + lc4 * 4);
        __syncthreads();
        for (int j = 0; j < 64; j++) {
            float s = 0.f;
            #pragma unroll
            for (int i = 0; i < 32; i++) s = fmaf(q[i], KT[j][i], s);
            float p = __expf(s - m);
            #pragma unroll
            for (int i = 0; i < 32; i++) acc[i] = fmaf(p, VT[j][i], acc[i]);
        }
    }

    float inv = 1.0f / l;
    float* op = ao + ((size_t)(b * SNODES + t)) * CCH + hh * HDIM;
    #pragma unroll
    for (int i = 0; i < 8; i++) {
        float4 v;
        v.x = acc[i * 4 + 0] * inv; v.y = acc[i * 4 + 1] * inv;
        v.z = acc[i * 4 + 2] * inv; v.w = acc[i * 4 + 3] * inv;
        ((float4*)op)[i] = v;
    }
}

// ---------------- pooling + head ----------------
__global__ void k_pool(const float* __restrict__ h, const int* __restrict__ batch,
                       float* __restrict__ pooled) {
    int gid = blockIdx.x * blockDim.x + threadIdx.x;
    if (gid >= NNODES * 32) return;
    int n = gid >> 5, c4 = gid & 31;
    int g = batch[n];
    float4 v = ((const float4*)h)[gid];
    float* pp = pooled + (size_t)g * CCH + c4 * 4;
    atomicAdd(pp + 0, v.x);
    atomicAdd(pp + 1, v.y);
    atomicAdd(pp + 2, v.z);
    atomicAdd(pp + 3, v.w);
}

__global__ void k_cnt(const int* __restrict__ batch, float* __restrict__ cnt) {
    int n = blockIdx.x * blockDim.x + threadIdx.x;
    if (n < NNODES) atomicAdd(&cnt[batch[n]], 1.0f);
}

__global__ __launch_bounds__(256) void k_head(const float* __restrict__ pooled,
                                              const float* __restrict__ cnt,
                                              const float* __restrict__ Wh,
                                              const float* __restrict__ bh,
                                              const float* __restrict__ Wo,
                                              const float* __restrict__ bo,
                                              float* __restrict__ out) {
    __shared__ float p[128];
    __shared__ float red[256];
    int g = blockIdx.x, t = threadIdx.x;
    if (t < 128) p[t] = pooled[g * CCH + t] / cnt[g];
    __syncthreads();
    float a = bh[t];
    for (int k = 0; k < 128; k++) a = fmaf(p[k], Wh[k * HIDDEN + t], a);
    float z = gelu_f(a);
    red[t] = z * Wo[t];
    __syncthreads();
    for (int s = 128; s > 0; s >>= 1) {
        if (t < s) red[t] += red[t + s];
        __syncthreads();
    }
    if (t == 0) out[g] = red[0] + bo[0];
}

// ---------------- launch ----------------
extern "C" void kernel_launch(void* const* d_in, const int* in_sizes, int n_in,
                              void* d_out, int out_size, void* d_ws, size_t ws_size,
                              hipStream_t stream) {
    const float* x      = (const float*)d_in[0];
    const float* pe     = (const float*)d_in[1];
    const int*   ei     = (const int*)d_in[2];
    const int*   batch  = (const int*)d_in[3];
    const float* W_emb  = (const float*)d_in[4];
    const float* b_emb  = (const float*)d_in[5];
    const float* gcn_w  = (const float*)d_in[6];
    const float* gcn_b  = (const float*)d_in[7];
    const float* in_w   = (const float*)d_in[8];
    const float* in_b   = (const float*)d_in[9];
    const float* out_w  = (const float*)d_in[10];
    const float* out_b  = (const float*)d_in[11];
    const float* mlp_w1 = (const float*)d_in[12];
    const float* mlp_b1 = (const float*)d_in[13];
    const float* mlp_w2 = (const float*)d_in[14];
    const float* mlp_b2 = (const float*)d_in[15];
    const float* g1     = (const float*)d_in[16];
    const float* be1    = (const float*)d_in[17];
    const float* g2     = (const float*)d_in[18];
    const float* be2    = (const float*)d_in[19];
    const float* g3     = (const float*)d_in[20];
    const float* be3    = (const float*)d_in[21];
    const float* W_hid  = (const float*)d_in[22];
    const float* b_hid  = (const float*)d_in[23];
    const float* W_out  = (const float*)d_in[24];
    const float* b_out  = (const float*)d_in[25];
    float* out = (float*)d_out;

    float* ws = (float*)d_ws;
    const size_t NC = (size_t)NNODES * CCH;
    float* dinv   = ws;
    float* h      = dinv + NNODES;
    float* A      = h + NC;
    float* Bb     = A + NC;
    float* qkv    = Bb + NC;                          // N*384
    float* part   = qkv + (size_t)NNODES * 384;       // 128*2*128
    float* sc     = part + 128 * 256;
    float* sh     = sc + CCH;
    float* pooled = sh + CCH;                         // B*C
    float* cnt    = pooled + (size_t)NB_GRAPH * CCH;  // B

    const int* srcp = ei;
    const int* dstp = ei + NEDGES;

    const int NC4 = NNODES * 32;  // number of float4 in an [N,C] buffer

    // degree -> dinv  (self loop counted via init to 1)
    k_fill<<<NNODES / 256, 256, 0, stream>>>(dinv, 1.0f, NNODES);
    k_deg_scatter<<<NEDGES / 256, 256, 0, stream>>>(dstp, dinv);
    k_rsqrt<<<NNODES / 256, 256, 0, stream>>>(dinv, NNODES);

    // embedding: h = [x|pe] @ W_emb + b_emb
    k_concat<<<(NNODES * 20) / 256, 256, 0, stream>>>(x, pe, qkv);
    k_gemm64<0, false><<<dim3(CCH / 64, NNODES / 64), 256, 0, stream>>>(
        qkv, W_emb, b_emb, h, NNODES, CCH, INDIM);

    for (int l = 0; l < NLAYERS; l++) {
        // --- GCN branch ---
        k_gemm64<0, false><<<dim3(CCH / 64, NNODES / 64), 256, 0, stream>>>(
            h, gcn_w + (size_t)l * CCH * CCH, nullptr, A, NNODES, CCH, CCH);
        k_locinit<<<NC4 / 256, 256, 0, stream>>>(A, dinv, gcn_b + l * CCH, Bb);
        k_gcn_scatter<<<(NEDGES * 4) / 256, 256, 0, stream>>>(srcp, dstp, dinv, A, Bb);
        k_bn_stats<<<128, 256, 0, stream>>>(Bb, h, part);
        k_bn_finalize<<<1, 128, 0, stream>>>(part, g1 + l * CCH, be1 + l * CCH, sc, sh);
        k_bn_apply<0><<<NC4 / 256, 256, 0, stream>>>(Bb, h, sc, sh, A);  // h1 = A

        // --- attention branch ---
        k_gemm64<0, true><<<dim3(384 / 64, NNODES / 64), 256, 0, stream>>>(
            h, in_w + (size_t)l * 384 * CCH, in_b + l * 384, qkv, NNODES, 384, CCH);
        k_attn<<<NB_GRAPH * NHEADS, 512, 0, stream>>>(qkv, Bb);  // ao = Bb
        k_gemm64<0, true><<<dim3(CCH / 64, NNODES / 64), 256, 0, stream>>>(
            Bb, out_w + (size_t)l * CCH * CCH, out_b + l * CCH, qkv, NNODES, CCH, CCH);
        k_bn_stats<<<128, 256, 0, stream>>>(qkv, h, part);
        k_bn_finalize<<<1, 128, 0, stream>>>(part, g2 + l * CCH, be2 + l * CCH, sc, sh);
        k_bn_apply<0><<<NC4 / 256, 256, 0, stream>>>(qkv, h, sc, sh, Bb);  // h2 = Bb

        // --- combine + MLP ---
        k_add<<<NC4 / 256, 256, 0, stream>>>(A, Bb);  // out = h1 + h2 (in A)
        k_gemm64<1, false><<<dim3(256 / 64, NNODES / 64), 256, 0, stream>>>(
            A, mlp_w1 + (size_t)l * CCH * 256, mlp_b1 + l * 256, qkv, NNODES, 256, CCH);
        k_gemm64<0, false><<<dim3(CCH / 64, NNODES / 64), 256, 0, stream>>>(
            qkv, mlp_w2 + (size_t)l * 256 * CCH, mlp_b2 + l * CCH, Bb, NNODES, CCH, 256);
        k_bn_stats<<<128, 256, 0, stream>>>(A, Bb, part);
        k_bn_finalize<<<1, 128, 0, stream>>>(part, g3 + l * CCH, be3 + l * CCH, sc, sh);
        k_bn_apply<2><<<NC4 / 256, 256, 0, stream>>>(A, Bb, sc, sh, h);  // h = gelu(bn)
    }

    // pooling + head
    hipMemsetAsync(pooled, 0, ((size_t)NB_GRAPH * CCH + NB_GRAPH) * sizeof(float), stream);
    k_pool<<<NC4 / 256, 256, 0, stream>>>(h, batch, pooled);
    k_cnt<<<NNODES / 256, 256, 0, stream>>>(batch, cnt);
    k_head<<<NB_GRAPH, 256, 0, stream>>>(pooled, cnt, W_hid, b_hid, W_out, b_out, out);
}

// Round 2
// 2018.332 us; speedup vs baseline: 6.2863x; 6.2863x over previous
//
#include <hip/hip_runtime.h>
#include <hip/hip_bf16.h>
#include <math.h>

#define NNODES 32768
#define NEDGES 524288
#define CCH 128
#define NLAYERS 3
#define NHEADS 4
#define HDIM 32
#define NB_GRAPH 64
#define SNODES 512
#define INDIM 80
#define HIDDEN 256
#define BNEPS 1e-5f

__device__ __forceinline__ float gelu_f(float x) {
    return 0.5f * x * (1.0f + erff(x * 0.70710678118654752f));
}

// ---------------- CSR build ----------------
__global__ void k_count(const int* __restrict__ dst, int* __restrict__ deg) {
    int e = blockIdx.x * blockDim.x + threadIdx.x;
    if (e < NEDGES) atomicAdd(&deg[dst[e]], 1);
}

__global__ void k_dinv_from_deg(const int* __restrict__ deg, float* __restrict__ dinv) {
    int i = blockIdx.x * blockDim.x + threadIdx.x;
    if (i < NNODES) dinv[i] = rsqrtf((float)(deg[i] + 1));  // +1 self loop
}

// single-block exclusive scan of 32768 counts (1024 thr x 32 each)
__global__ __launch_bounds__(1024) void k_scan(const int* __restrict__ deg,
                                               int* __restrict__ rowptr,
                                               int* __restrict__ cursor) {
    __shared__ int sa[1024], sb[1024];
    int t = threadIdx.x;
    int base = t * 32;
    int local[32];
    int s = 0;
    #pragma unroll
    for (int i = 0; i < 32; i++) { local[i] = s; s += deg[base + i]; }
    sa[t] = s;
    __syncthreads();
    int* sp = sa; int* dp = sb;
    for (int off = 1; off < 1024; off <<= 1) {
        dp[t] = (t >= off) ? sp[t] + sp[t - off] : sp[t];
        __syncthreads();
        int* tmp = sp; sp = dp; dp = tmp;
    }
    int excl = (t == 0) ? 0 : sp[t - 1];
    #pragma unroll
    for (int i = 0; i < 32; i++) {
        int v = excl + local[i];
        rowptr[base + i] = v;
        cursor[base + i] = v;
    }
    if (t == 1023) rowptr[NNODES] = sp[1023];
}

__global__ void k_fill_edges(const int* __restrict__ src, const int* __restrict__ dst,
                             int* __restrict__ cursor, int* __restrict__ col) {
    int e = blockIdx.x * blockDim.x + threadIdx.x;
    if (e >= NEDGES) return;
    int pos = atomicAdd(&cursor[dst[e]], 1);
    col[pos] = src[e];
}

// ---------------- utility ----------------
// concat [x | pe] -> out [N, 80], processed as float4 (20 per row)
__global__ void k_concat(const float* __restrict__ x, const float* __restrict__ pe,
                         float* __restrict__ out) {
    int gid = blockIdx.x * blockDim.x + threadIdx.x;
    if (gid >= NNODES * 20) return;
    int n = gid / 20, q = gid % 20;
    float4 v;
    if (q < 16) v = ((const float4*)x)[(size_t)n * 16 + q];
    else        v = ((const float4*)pe)[(size_t)n * 4 + (q - 16)];
    ((float4*)out)[gid] = v;
}

// ---------------- GEMM: C[M,N] = act((A[M,K] @ B + bias) * rowscale) ----------------
// TRANSB=false: B is [K,N] row-major.  TRANSB=true: B is [N,K] row-major (A @ B^T).
// ACT: 0 = none, 1 = relu
template<int ACT, bool TRANSB>
__global__ __launch_bounds__(256) void k_gemm64(
        const float* __restrict__ A, const float* __restrict__ B,
        const float* __restrict__ bias, const float* __restrict__ rowscale,
        float* __restrict__ C, int M, int N, int K) {
    __shared__ float As[16][68];
    __shared__ float Bs[16][68];
    const int tid = threadIdx.x;
    const int bm = blockIdx.y * 64, bn = blockIdx.x * 64;
    const int tx = tid & 15, ty = tid >> 4;
    float acc[4][4] = {};

    for (int k0 = 0; k0 < K; k0 += 16) {
        {
            int m = tid >> 2, k = (tid & 3) * 4;
            float4 v = *(const float4*)(A + (size_t)(bm + m) * K + k0 + k);
            As[k][m] = v.x; As[k + 1][m] = v.y; As[k + 2][m] = v.z; As[k + 3][m] = v.w;
        }
        if (!TRANSB) {
            int k = tid >> 4, n = (tid & 15) * 4;
            float4 v = *(const float4*)(B + (size_t)(k0 + k) * N + bn + n);
            Bs[k][n] = v.x; Bs[k][n + 1] = v.y; Bs[k][n + 2] = v.z; Bs[k][n + 3] = v.w;
        } else {
            int n = tid >> 2, k = (tid & 3) * 4;
            float4 v = *(const float4*)(B + (size_t)(bn + n) * K + k0 + k);
            Bs[k][n] = v.x; Bs[k + 1][n] = v.y; Bs[k + 2][n] = v.z; Bs[k + 3][n] = v.w;
        }
        __syncthreads();
        #pragma unroll
        for (int k = 0; k < 16; k++) {
            float4 av = *(const float4*)&As[k][ty * 4];
            float4 bv = *(const float4*)&Bs[k][tx * 4];
            float a0[4] = {av.x, av.y, av.z, av.w};
            float b0[4] = {bv.x, bv.y, bv.z, bv.w};
            #pragma unroll
            for (int i = 0; i < 4; i++)
                #pragma unroll
                for (int j = 0; j < 4; j++)
                    acc[i][j] = fmaf(a0[i], b0[j], acc[i][j]);
        }
        __syncthreads();
    }

    float bv[4];
    #pragma unroll
    for (int j = 0; j < 4; j++) bv[j] = bias ? bias[bn + tx * 4 + j] : 0.0f;
    #pragma unroll
    for (int i = 0; i < 4; i++) {
        int row = bm + ty * 4 + i;
        float rs = rowscale ? rowscale[row] : 1.0f;
        float4 o;
        float r[4];
        #pragma unroll
        for (int j = 0; j < 4; j++) {
            float v = (acc[i][j] + bv[j]) * rs;
            if (ACT == 1) v = fmaxf(v, 0.0f);
            r[j] = v;
        }
        o.x = r[0]; o.y = r[1]; o.z = r[2]; o.w = r[3];
        *(float4*)(C + (size_t)row * N + bn + tx * 4) = o;
    }
}

// ---------------- GCN gather ----------------
// xws[i] = (h @ W) * dinv[i]  (done in GEMM epilogue)
// loc[d] = dinv[d] * (xws[d] + sum_{e: dst=d} xws[col[e]]) + bias
__global__ __launch_bounds__(256) void k_gcn_gather(
        const int* __restrict__ rowptr, const int* __restrict__ col,
        const float* __restrict__ xws, const float* __restrict__ dinv,
        const float* __restrict__ bias, float* __restrict__ loc) {
    int t = threadIdx.x;
    int node = blockIdx.x * 8 + (t >> 5);
    int q = t & 31;
    int r0 = rowptr[node], r1 = rowptr[node + 1];
    float4 acc = ((const float4*)(xws + (size_t)node * CCH))[q];  // self loop
    for (int j = r0; j < r1; j++) {
        int s = col[j];
        float4 v = ((const float4*)(xws + (size_t)s * CCH))[q];
        acc.x += v.x; acc.y += v.y; acc.z += v.z; acc.w += v.w;
    }
    float dv = dinv[node];
    float4 b4 = ((const float4*)bias)[q];
    float4 o;
    o.x = fmaf(acc.x, dv, b4.x); o.y = fmaf(acc.y, dv, b4.y);
    o.z = fmaf(acc.z, dv, b4.z); o.w = fmaf(acc.w, dv, b4.w);
    ((float4*)(loc + (size_t)node * CCH))[q] = o;
}

// ---------------- BatchNorm ----------------
__global__ __launch_bounds__(256) void k_bn_stats(const float* __restrict__ a,
                                                  const float* __restrict__ b,
                                                  float* __restrict__ part) {
    __shared__ float s1[256], s2[256];
    int t = threadIdx.x, blk = blockIdx.x;
    int c = t & 127, half = t >> 7;
    float sum = 0.f, sq = 0.f;
    for (int i = 0; i < 128; i++) {
        size_t r = (size_t)blk * 256 + half + 2 * i;
        float v = a[r * CCH + c] + b[r * CCH + c];
        sum += v;
        sq = fmaf(v, v, sq);
    }
    s1[t] = sum; s2[t] = sq;
    __syncthreads();
    if (t < 128) {
        part[blk * 256 + t]       = s1[t] + s1[t + 128];
        part[blk * 256 + 128 + t] = s2[t] + s2[t + 128];
    }
}

__global__ void k_bn_finalize(const float* __restrict__ part, const float* __restrict__ g,
                              const float* __restrict__ be, float* __restrict__ sc,
                              float* __restrict__ sh) {
    int c = threadIdx.x;  // 128 threads
    float s = 0.f, sq = 0.f;
    for (int bk = 0; bk < 128; bk++) {
        s  += part[bk * 256 + c];
        sq += part[bk * 256 + 128 + c];
    }
    float mu = s / (float)NNODES;
    float var = sq / (float)NNODES - mu * mu;
    float rs = rsqrtf(var + BNEPS);
    float gg = g[c] * rs;
    sc[c] = gg;
    sh[c] = be[c] - mu * gg;
}

template<int ACT>
__global__ void k_bn_apply(const float* __restrict__ a, const float* __restrict__ b,
                           const float* __restrict__ sc, const float* __restrict__ sh,
                           float* __restrict__ out) {
    int gid = blockIdx.x * blockDim.x + threadIdx.x;
    if (gid >= NNODES * 32) return;
    int c = (gid & 31) * 4;
    float4 av = ((const float4*)a)[gid];
    float4 bv = ((const float4*)b)[gid];
    float r[4];
    float xs[4] = {av.x + bv.x, av.y + bv.y, av.z + bv.z, av.w + bv.w};
    #pragma unroll
    for (int j = 0; j < 4; j++) {
        float v = fmaf(xs[j], sc[c + j], sh[c + j]);
        if (ACT == 2) v = gelu_f(v);
        r[j] = v;
    }
    float4 o = {r[0], r[1], r[2], r[3]};
    ((float4*)out)[gid] = o;
}

__global__ void k_add(float* __restrict__ a, const float* __restrict__ b) {
    int gid = blockIdx.x * blockDim.x + threadIdx.x;
    if (gid >= NNODES * 32) return;
    float4 av = ((float4*)a)[gid];
    float4 bv = ((const float4*)b)[gid];
    av.x += bv.x; av.y += bv.y; av.z += bv.z; av.w += bv.w;
    ((float4*)a)[gid] = av;
}

// ---------------- attention ----------------
__global__ __launch_bounds__(512) void k_attn(const float* __restrict__ qkv,
                                              float* __restrict__ ao) {
    __shared__ float KT[64][32];
    __shared__ float VT[64][32];
    const int bh = blockIdx.x;
    const int b = bh >> 2, hh = bh & 3;
    const int t = threadIdx.x;
    const float scale = 0.17677669529663689f;  // 1/sqrt(32)

    const float* qp = qkv + ((size_t)(b * SNODES + t)) * 384 + hh * HDIM;
    float q[32];
    #pragma unroll
    for (int i = 0; i < 8; i++) {
        float4 v = ((const float4*)qp)[i];
        q[i * 4 + 0] = v.x * scale; q[i * 4 + 1] = v.y * scale;
        q[i * 4 + 2] = v.z * scale; q[i * 4 + 3] = v.w * scale;
    }

    const int lrow = t >> 3, lc4 = t & 7;
    float m = -INFINITY, l = 0.f;

    for (int j0 = 0; j0 < SNODES; j0 += 64) {
        __syncthreads();
        ((float4*)KT[lrow])[lc4] = *(const float4*)(qkv +
            ((size_t)(b * SNODES + j0 + lrow)) * 384 + CCH + hh * HDIM + lc4 * 4);
        __syncthreads();
        for (int j = 0; j < 64; j++) {
            float s = 0.f;
            #pragma unroll
            for (int i = 0; i < 32; i++) s = fmaf(q[i], KT[j][i], s);
            float mn = fmaxf(m, s);
            l = l * __expf(m - mn) + __expf(s - mn);
            m = mn;
        }
    }

    float acc[32];
    #pragma unroll
    for (int i = 0; i < 32; i++) acc[i] = 0.f;

    for (int j0 = 0; j0 < SNODES; j0 += 64) {
        __syncthreads();
        ((float4*)KT[lrow])[lc4] = *(const float4*)(qkv +
            ((size_t)(b * SNODES + j0 + lrow)) * 384 + CCH + hh * HDIM + lc4 * 4);
        ((float4*)VT[lrow])[lc4] = *(const float4*)(qkv +
            ((size_t)(b * SNODES + j0 + lrow)) * 384 + 2 * CCH + hh * HDIM + lc4 * 4);
        __syncthreads();
        for (int j = 0; j < 64; j++) {
            float s = 0.f;
            #pragma unroll
            for (int i = 0; i < 32; i++) s = fmaf(q[i], KT[j][i], s);
            float p = __expf(s - m);
            #pragma unroll
            for (int i = 0; i < 32; i++) acc[i] = fmaf(p, VT[j][i], acc[i]);
        }
    }

    float inv = 1.0f / l;
    float* op = ao + ((size_t)(b * SNODES + t)) * CCH + hh * HDIM;
    #pragma unroll
    for (int i = 0; i < 8; i++) {
        float4 v;
        v.x = acc[i * 4 + 0] * inv; v.y = acc[i * 4 + 1] * inv;
        v.z = acc[i * 4 + 2] * inv; v.w = acc[i * 4 + 3] * inv;
        ((float4*)op)[i] = v;
    }
}

// ---------------- pooling + head ----------------
__global__ void k_pool(const float* __restrict__ h, const int* __restrict__ batch,
                       float* __restrict__ pooled) {
    int gid = blockIdx.x * blockDim.x + threadIdx.x;
    if (gid >= NNODES * 32) return;
    int n = gid >> 5, c4 = gid & 31;
    int g = batch[n];
    float4 v = ((const float4*)h)[gid];
    float* pp = pooled + (size_t)g * CCH + c4 * 4;
    atomicAdd(pp + 0, v.x);
    atomicAdd(pp + 1, v.y);
    atomicAdd(pp + 2, v.z);
    atomicAdd(pp + 3, v.w);
}

__global__ void k_cnt(const int* __restrict__ batch, float* __restrict__ cnt) {
    int n = blockIdx.x * blockDim.x + threadIdx.x;
    if (n < NNODES) atomicAdd(&cnt[batch[n]], 1.0f);
}

__global__ __launch_bounds__(256) void k_head(const float* __restrict__ pooled,
                                              const float* __restrict__ cnt,
                                              const float* __restrict__ Wh,
                                              const float* __restrict__ bh,
                                              const float* __restrict__ Wo,
                                              const float* __restrict__ bo,
                                              float* __restrict__ out) {
    __shared__ float p[128];
    __shared__ float red[256];
    int g = blockIdx.x, t = threadIdx.x;
    if (t < 128) p[t] = pooled[g * CCH + t] / cnt[g];
    __syncthreads();
    float a = bh[t];
    for (int k = 0; k < 128; k++) a = fmaf(p[k], Wh[k * HIDDEN + t], a);
    float z = gelu_f(a);
    red[t] = z * Wo[t];
    __syncthreads();
    for (int s = 128; s > 0; s >>= 1) {
        if (t < s) red[t] += red[t + s];
        __syncthreads();
    }
    if (t == 0) out[g] = red[0] + bo[0];
}

// ---------------- launch ----------------
extern "C" void kernel_launch(void* const* d_in, const int* in_sizes, int n_in,
                              void* d_out, int out_size, void* d_ws, size_t ws_size,
                              hipStream_t stream) {
    const float* x      = (const float*)d_in[0];
    const float* pe     = (const float*)d_in[1];
    const int*   ei     = (const int*)d_in[2];
    const int*   batch  = (const int*)d_in[3];
    const float* W_emb  = (const float*)d_in[4];
    const float* b_emb  = (const float*)d_in[5];
    const float* gcn_w  = (const float*)d_in[6];
    const float* gcn_b  = (const float*)d_in[7];
    const float* in_w   = (const float*)d_in[8];
    const float* in_b   = (const float*)d_in[9];
    const float* out_w  = (const float*)d_in[10];
    const float* out_b  = (const float*)d_in[11];
    const float* mlp_w1 = (const float*)d_in[12];
    const float* mlp_b1 = (const float*)d_in[13];
    const float* mlp_w2 = (const float*)d_in[14];
    const float* mlp_b2 = (const float*)d_in[15];
    const float* g1     = (const float*)d_in[16];
    const float* be1    = (const float*)d_in[17];
    const float* g2     = (const float*)d_in[18];
    const float* be2    = (const float*)d_in[19];
    const float* g3     = (const float*)d_in[20];
    const float* be3    = (const float*)d_in[21];
    const float* W_hid  = (const float*)d_in[22];
    const float* b_hid  = (const float*)d_in[23];
    const float* W_out  = (const float*)d_in[24];
    const float* b_out  = (const float*)d_in[25];
    float* out = (float*)d_out;

    float* ws = (float*)d_ws;
    const size_t NC = (size_t)NNODES * CCH;
    float* dinv   = ws;
    float* h      = dinv + NNODES;
    float* A      = h + NC;
    float* Bb     = A + NC;
    float* qkv    = Bb + NC;                          // N*384
    float* part   = qkv + (size_t)NNODES * 384;       // 128*256
    float* sc     = part + 128 * 256;
    float* sh     = sc + CCH;
    float* pooled = sh + CCH;                         // B*C
    float* cnt    = pooled + (size_t)NB_GRAPH * CCH;  // B
    int*   ideg   = (int*)(cnt + NB_GRAPH);           // N
    int*   rowptr = ideg + NNODES;                    // N+1
    int*   cursor = rowptr + NNODES + 1;              // N
    int*   col    = cursor + NNODES;                  // E

    const int* srcp = ei;
    const int* dstp = ei + NEDGES;

    const int NC4 = NNODES * 32;  // float4 count of an [N,C] buffer

    // ---- CSR build + dinv ----
    hipMemsetAsync(ideg, 0, NNODES * sizeof(int), stream);
    k_count<<<NEDGES / 256, 256, 0, stream>>>(dstp, ideg);
    k_dinv_from_deg<<<NNODES / 256, 256, 0, stream>>>(ideg, dinv);
    k_scan<<<1, 1024, 0, stream>>>(ideg, rowptr, cursor);
    k_fill_edges<<<NEDGES / 256, 256, 0, stream>>>(srcp, dstp, cursor, col);

    // embedding: h = [x|pe] @ W_emb + b_emb
    k_concat<<<(NNODES * 20) / 256, 256, 0, stream>>>(x, pe, qkv);
    k_gemm64<0, false><<<dim3(CCH / 64, NNODES / 64), 256, 0, stream>>>(
        qkv, W_emb, b_emb, nullptr, h, NNODES, CCH, INDIM);

    for (int l = 0; l < NLAYERS; l++) {
        // --- GCN branch: xws = (h @ W) * dinv  (row-scaled in epilogue) ---
        k_gemm64<0, false><<<dim3(CCH / 64, NNODES / 64), 256, 0, stream>>>(
            h, gcn_w + (size_t)l * CCH * CCH, nullptr, dinv, A, NNODES, CCH, CCH);
        k_gcn_gather<<<NNODES / 8, 256, 0, stream>>>(
            rowptr, col, A, dinv, gcn_b + l * CCH, Bb);
        k_bn_stats<<<128, 256, 0, stream>>>(Bb, h, part);
        k_bn_finalize<<<1, 128, 0, stream>>>(part, g1 + l * CCH, be1 + l * CCH, sc, sh);
        k_bn_apply<0><<<NC4 / 256, 256, 0, stream>>>(Bb, h, sc, sh, A);  // h1 = A

        // --- attention branch ---
        k_gemm64<0, true><<<dim3(384 / 64, NNODES / 64), 256, 0, stream>>>(
            h, in_w + (size_t)l * 384 * CCH, in_b + l * 384, nullptr, qkv, NNODES, 384, CCH);
        k_attn<<<NB_GRAPH * NHEADS, 512, 0, stream>>>(qkv, Bb);  // ao = Bb
        k_gemm64<0, true><<<dim3(CCH / 64, NNODES / 64), 256, 0, stream>>>(
            Bb, out_w + (size_t)l * CCH * CCH, out_b + l * CCH, nullptr, qkv, NNODES, CCH, CCH);
        k_bn_stats<<<128, 256, 0, stream>>>(qkv, h, part);
        k_bn_finalize<<<1, 128, 0, stream>>>(part, g2 + l * CCH, be2 + l * CCH, sc, sh);
        k_bn_apply<0><<<NC4 / 256, 256, 0, stream>>>(qkv, h, sc, sh, Bb);  // h2 = Bb

        // --- combine + MLP ---
        k_add<<<NC4 / 256, 256, 0, stream>>>(A, Bb);  // out = h1 + h2 (in A)
        k_gemm64<1, false><<<dim3(256 / 64, NNODES / 64), 256, 0, stream>>>(
            A, mlp_w1 + (size_t)l * CCH * 256, mlp_b1 + l * 256, nullptr, qkv, NNODES, 256, CCH);
        k_gemm64<0, false><<<dim3(CCH / 64, NNODES / 64), 256, 0, stream>>>(
            qkv, mlp_w2 + (size_t)l * 256 * CCH, mlp_b2 + l * CCH, nullptr, Bb, NNODES, CCH, 256);
        k_bn_stats<<<128, 256, 0, stream>>>(A, Bb, part);
        k_bn_finalize<<<1, 128, 0, stream>>>(part, g3 + l * CCH, be3 + l * CCH, sc, sh);
        k_bn_apply<2><<<NC4 / 256, 256, 0, stream>>>(A, Bb, sc, sh, h);  // h = gelu(bn)
    }

    // pooling + head
    hipMemsetAsync(pooled, 0, ((size_t)NB_GRAPH * CCH + NB_GRAPH) * sizeof(float), stream);
    k_pool<<<NC4 / 256, 256, 0, stream>>>(h, batch, pooled);
    k_cnt<<<NNODES / 256, 256, 0, stream>>>(batch, cnt);
    k_head<<<NB_GRAPH, 256, 0, stream>>>(pooled, cnt, W_hid, b_hid, W_out, b_out, out);
}

// Round 4
// 1410.750 us; speedup vs baseline: 8.9936x; 1.4307x over previous
//
#include <hip/hip_runtime.h>
#include <hip/hip_bf16.h>
#include <math.h>

#define NNODES 32768
#define NEDGES 524288
#define CCH 128
#define NLAYERS 3
#define NHEADS 4
#define HDIM 32
#define NB_GRAPH 64
#define SNODES 512
#define INDIM 80
#define HIDDEN 256
#define BNEPS 1e-5f

typedef _Float16 f16;
typedef f16 half8_t __attribute__((ext_vector_type(8)));
typedef f16 half4_t __attribute__((ext_vector_type(4)));
typedef float float4_t __attribute__((ext_vector_type(4)));

__device__ __forceinline__ float gelu_f(float x) {
    return 0.5f * x * (1.0f + erff(x * 0.70710678118654752f));
}

// ---------------- CSR build ----------------
__global__ void k_count(const int* __restrict__ dst, int* __restrict__ deg) {
    int e = blockIdx.x * blockDim.x + threadIdx.x;
    if (e < NEDGES) atomicAdd(&deg[dst[e]], 1);
}

__global__ void k_dinv_from_deg(const int* __restrict__ deg, float* __restrict__ dinv) {
    int i = blockIdx.x * blockDim.x + threadIdx.x;
    if (i < NNODES) dinv[i] = rsqrtf((float)(deg[i] + 1));  // +1 self loop
}

// single-block exclusive scan of 32768 counts (1024 thr x 32 each)
__global__ __launch_bounds__(1024) void k_scan(const int* __restrict__ deg,
                                               int* __restrict__ rowptr,
                                               int* __restrict__ cursor) {
    __shared__ int sa[1024], sb[1024];
    int t = threadIdx.x;
    int base = t * 32;
    int local[32];
    int s = 0;
    #pragma unroll
    for (int i = 0; i < 32; i++) { local[i] = s; s += deg[base + i]; }
    sa[t] = s;
    __syncthreads();
    int* sp = sa; int* dp = sb;
    for (int off = 1; off < 1024; off <<= 1) {
        dp[t] = (t >= off) ? sp[t] + sp[t - off] : sp[t];
        __syncthreads();
        int* tmp = sp; sp = dp; dp = tmp;
    }
    int excl = (t == 0) ? 0 : sp[t - 1];
    #pragma unroll
    for (int i = 0; i < 32; i++) {
        int v = excl + local[i];
        rowptr[base + i] = v;
        cursor[base + i] = v;
    }
    if (t == 1023) rowptr[NNODES] = sp[1023];
}

__global__ void k_fill_edges(const int* __restrict__ src, const int* __restrict__ dst,
                             int* __restrict__ cursor, int* __restrict__ col) {
    int e = blockIdx.x * blockDim.x + threadIdx.x;
    if (e >= NEDGES) return;
    int pos = atomicAdd(&cursor[dst[e]], 1);
    col[pos] = src[e];
}

// ---------------- utility ----------------
__global__ void k_concat(const float* __restrict__ x, const float* __restrict__ pe,
                         float* __restrict__ out) {
    int gid = blockIdx.x * blockDim.x + threadIdx.x;
    if (gid >= NNODES * 20) return;
    int n = gid / 20, q = gid % 20;
    float4 v;
    if (q < 16) v = ((const float4*)x)[(size_t)n * 16 + q];
    else        v = ((const float4*)pe)[(size_t)n * 4 + (q - 16)];
    ((float4*)out)[gid] = v;
}

// ---------------- GEMM: C[M,N] = act((A[M,K] @ B + bias) * rowscale) ----------------
template<int ACT, bool TRANSB>
__global__ __launch_bounds__(256) void k_gemm64(
        const float* __restrict__ A, const float* __restrict__ B,
        const float* __restrict__ bias, const float* __restrict__ rowscale,
        float* __restrict__ C, int M, int N, int K) {
    __shared__ float As[16][68];
    __shared__ float Bs[16][68];
    const int tid = threadIdx.x;
    const int bm = blockIdx.y * 64, bn = blockIdx.x * 64;
    const int tx = tid & 15, ty = tid >> 4;
    float acc[4][4] = {};

    for (int k0 = 0; k0 < K; k0 += 16) {
        {
            int m = tid >> 2, k = (tid & 3) * 4;
            float4 v = *(const float4*)(A + (size_t)(bm + m) * K + k0 + k);
            As[k][m] = v.x; As[k + 1][m] = v.y; As[k + 2][m] = v.z; As[k + 3][m] = v.w;
        }
        if (!TRANSB) {
            int k = tid >> 4, n = (tid & 15) * 4;
            float4 v = *(const float4*)(B + (size_t)(k0 + k) * N + bn + n);
            Bs[k][n] = v.x; Bs[k][n + 1] = v.y; Bs[k][n + 2] = v.z; Bs[k][n + 3] = v.w;
        } else {
            int n = tid >> 2, k = (tid & 3) * 4;
            float4 v = *(const float4*)(B + (size_t)(bn + n) * K + k0 + k);
            Bs[k][n] = v.x; Bs[k + 1][n] = v.y; Bs[k + 2][n] = v.z; Bs[k + 3][n] = v.w;
        }
        __syncthreads();
        #pragma unroll
        for (int k = 0; k < 16; k++) {
            float4 av = *(const float4*)&As[k][ty * 4];
            float4 bv = *(const float4*)&Bs[k][tx * 4];
            float a0[4] = {av.x, av.y, av.z, av.w};
            float b0[4] = {bv.x, bv.y, bv.z, bv.w};
            #pragma unroll
            for (int i = 0; i < 4; i++)
                #pragma unroll
                for (int j = 0; j < 4; j++)
                    acc[i][j] = fmaf(a0[i], b0[j], acc[i][j]);
        }
        __syncthreads();
    }

    float bv[4];
    #pragma unroll
    for (int j = 0; j < 4; j++) bv[j] = bias ? bias[bn + tx * 4 + j] : 0.0f;
    #pragma unroll
    for (int i = 0; i < 4; i++) {
        int row = bm + ty * 4 + i;
        float rs = rowscale ? rowscale[row] : 1.0f;
        float4 o;
        float r[4];
        #pragma unroll
        for (int j = 0; j < 4; j++) {
            float v = (acc[i][j] + bv[j]) * rs;
            if (ACT == 1) v = fmaxf(v, 0.0f);
            r[j] = v;
        }
        o.x = r[0]; o.y = r[1]; o.z = r[2]; o.w = r[3];
        *(float4*)(C + (size_t)row * N + bn + tx * 4) = o;
    }
}

// ---------------- GCN gather ----------------
__global__ __launch_bounds__(256) void k_gcn_gather(
        const int* __restrict__ rowptr, const int* __restrict__ col,
        const float* __restrict__ xws, const float* __restrict__ dinv,
        const float* __restrict__ bias, float* __restrict__ loc) {
    int t = threadIdx.x;
    int node = blockIdx.x * 8 + (t >> 5);
    int q = t & 31;
    int r0 = rowptr[node], r1 = rowptr[node + 1];
    float4 acc = ((const float4*)(xws + (size_t)node * CCH))[q];  // self loop
    for (int j = r0; j < r1; j++) {
        int s = col[j];
        float4 v = ((const float4*)(xws + (size_t)s * CCH))[q];
        acc.x += v.x; acc.y += v.y; acc.z += v.z; acc.w += v.w;
    }
    float dv = dinv[node];
    float4 b4 = ((const float4*)bias)[q];
    float4 o;
    o.x = fmaf(acc.x, dv, b4.x); o.y = fmaf(acc.y, dv, b4.y);
    o.z = fmaf(acc.z, dv, b4.z); o.w = fmaf(acc.w, dv, b4.w);
    ((float4*)(loc + (size_t)node * CCH))[q] = o;
}

// ---------------- BatchNorm ----------------
__global__ __launch_bounds__(256) void k_bn_stats(const float* __restrict__ a,
                                                  const float* __restrict__ b,
                                                  float* __restrict__ part) {
    __shared__ float s1[256], s2[256];
    int t = threadIdx.x, blk = blockIdx.x;
    int c = t & 127, half = t >> 7;
    float sum = 0.f, sq = 0.f;
    for (int i = 0; i < 128; i++) {
        size_t r = (size_t)blk * 256 + half + 2 * i;
        float v = a[r * CCH + c] + b[r * CCH + c];
        sum += v;
        sq = fmaf(v, v, sq);
    }
    s1[t] = sum; s2[t] = sq;
    __syncthreads();
    if (t < 128) {
        part[blk * 256 + t]       = s1[t] + s1[t + 128];
        part[blk * 256 + 128 + t] = s2[t] + s2[t + 128];
    }
}

__global__ void k_bn_finalize(const float* __restrict__ part, const float* __restrict__ g,
                              const float* __restrict__ be, float* __restrict__ sc,
                              float* __restrict__ sh) {
    int c = threadIdx.x;  // 128 threads
    float s = 0.f, sq = 0.f;
    for (int bk = 0; bk < 128; bk++) {
        s  += part[bk * 256 + c];
        sq += part[bk * 256 + 128 + c];
    }
    float mu = s / (float)NNODES;
    float var = sq / (float)NNODES - mu * mu;
    float rs = rsqrtf(var + BNEPS);
    float gg = g[c] * rs;
    sc[c] = gg;
    sh[c] = be[c] - mu * gg;
}

template<int ACT>
__global__ void k_bn_apply(const float* __restrict__ a, const float* __restrict__ b,
                           const float* __restrict__ sc, const float* __restrict__ sh,
                           float* __restrict__ out) {
    int gid = blockIdx.x * blockDim.x + threadIdx.x;
    if (gid >= NNODES * 32) return;
    int c = (gid & 31) * 4;
    float4 av = ((const float4*)a)[gid];
    float4 bv = ((const float4*)b)[gid];
    float r[4];
    float xs[4] = {av.x + bv.x, av.y + bv.y, av.z + bv.z, av.w + bv.w};
    #pragma unroll
    for (int j = 0; j < 4; j++) {
        float v = fmaf(xs[j], sc[c + j], sh[c + j]);
        if (ACT == 2) v = gelu_f(v);
        r[j] = v;
    }
    float4 o = {r[0], r[1], r[2], r[3]};
    ((float4*)out)[gid] = o;
}

__global__ void k_add(float* __restrict__ a, const float* __restrict__ b) {
    int gid = blockIdx.x * blockDim.x + threadIdx.x;
    if (gid >= NNODES * 32) return;
    float4 av = ((float4*)a)[gid];
    float4 bv = ((const float4*)b)[gid];
    av.x += bv.x; av.y += bv.y; av.z += bv.z; av.w += bv.w;
    ((float4*)a)[gid] = av;
}

// ---------------- MFMA attention ----------------
// one block per (graph b, head hh); 4 waves; wave w handles queries w*128..w*128+127
// f16 inputs, fp32 accum. Swapped QK^T (D'[key][q]) so softmax is lane-local + 2 shfl.
__global__ __launch_bounds__(256, 1) void k_attn_mfma(const float* __restrict__ qkv,
                                                      float* __restrict__ ao) {
    __shared__ f16 Ks[512 * 40];   // K rows padded to 40 f16 (80B)
    __shared__ f16 VT[32 * 512];   // V^T [hd][key], keys in 4-chunks rotated by hd
    const int bh = blockIdx.x;
    const int b = bh >> 2, hh = bh & 3;
    const int t = threadIdx.x;
    const int lane = t & 63, wave = t >> 6;
    const int g = lane >> 4, q16 = lane & 15;
    const float scale = 0.17677669529663689f;  // 1/sqrt(32)

    const float* base = qkv + (size_t)b * SNODES * 384;

    // ---- stage K (f16, 80B rows) ----
    #pragma unroll
    for (int it = 0; it < 8; it++) {
        int u = it * 256 + t;
        int row = u >> 2, c = u & 3;
        const float* gp = base + (size_t)row * 384 + CCH + hh * HDIM + c * 8;
        float4 v0 = *(const float4*)gp;
        float4 v1 = *(const float4*)(gp + 4);
        half8_t hv;
        hv[0] = (f16)v0.x; hv[1] = (f16)v0.y; hv[2] = (f16)v0.z; hv[3] = (f16)v0.w;
        hv[4] = (f16)v1.x; hv[5] = (f16)v1.y; hv[6] = (f16)v1.z; hv[7] = (f16)v1.w;
        *(half8_t*)(Ks + row * 40 + c * 8) = hv;
    }

    // ---- stage V^T via 4x4 in-wave shuffle transpose ----
    // thread: node n (8 lanes consecutive read same node's 128B), hd chunk c = t&7
    #pragma unroll
    for (int it = 0; it < 16; it++) {
        int j4 = (t >> 3) & 3;                       // node-within-4 after transpose
        int n  = it * 32 + ((t >> 5) & 7) * 4 + j4;  // node this thread LOADS
        int c  = t & 7;
        float4 v = *(const float4*)(base + (size_t)n * 384 + 2 * CCH + hh * HDIM + c * 4);
        float4 u1;
        u1.x = __shfl_xor(v.x, 8); u1.y = __shfl_xor(v.y, 8);
        u1.z = __shfl_xor(v.z, 8); u1.w = __shfl_xor(v.w, 8);
        float4 w;
        if ((t & 8) == 0) { w.x = v.x;  w.y = u1.x; w.z = v.z;  w.w = u1.z; }
        else              { w.x = u1.y; w.y = v.y;  w.z = u1.w; w.w = v.w;  }
        float4 u2;
        u2.x = __shfl_xor(w.x, 16); u2.y = __shfl_xor(w.y, 16);
        u2.z = __shfl_xor(w.z, 16); u2.w = __shfl_xor(w.w, 16);
        float4 o;
        if ((t & 16) == 0) { o.x = w.x;  o.y = w.y;  o.z = u2.x; o.w = u2.y; }
        else               { o.x = u2.z; o.y = u2.w; o.z = w.z;  o.w = w.w;  }
        // o = V[n0+0..3][hd], hd = c*4 + j4
        int hd = c * 4 + j4;
        int n0 = it * 32 + ((t >> 5) & 7) * 4;
        half4_t pk;
        pk[0] = (f16)o.x; pk[1] = (f16)o.y; pk[2] = (f16)o.z; pk[3] = (f16)o.w;
        int pos = ((n0 >> 2) + hd) & 127;
        *(half4_t*)(VT + hd * 512 + pos * 4) = pk;
    }
    __syncthreads();

    for (int j = 0; j < 8; j++) {
        int qt = wave * 8 + j;  // q-tile of 16 queries

        // Q B-frag: lane holds Q[qt*16 + q16][hd = 8g..8g+7] * scale
        const float* qp = base + (size_t)(qt * 16 + q16) * 384 + hh * HDIM + g * 8;
        float4 q0 = *(const float4*)qp;
        float4 q1 = *(const float4*)(qp + 4);
        half8_t qf;
        qf[0] = (f16)(q0.x * scale); qf[1] = (f16)(q0.y * scale);
        qf[2] = (f16)(q0.z * scale); qf[3] = (f16)(q0.w * scale);
        qf[4] = (f16)(q1.x * scale); qf[5] = (f16)(q1.y * scale);
        qf[6] = (f16)(q1.z * scale); qf[7] = (f16)(q1.w * scale);

        // QK^T: acc[kt] holds D'[key 4g+r + 16kt][q = q16]
        float4_t acc[32];
        #pragma unroll
        for (int kt = 0; kt < 32; kt++) {
            half8_t kf = *(half8_t*)(Ks + (kt * 16 + q16) * 40 + g * 8);
            float4_t z = {0.f, 0.f, 0.f, 0.f};
            acc[kt] = __builtin_amdgcn_mfma_f32_16x16x32_f16(kf, qf, z, 0, 0, 0);
        }

        // softmax over the row of query q16 (512 scores spread over lanes q16+16*g)
        float m = -1e30f;
        #pragma unroll
        for (int kt = 0; kt < 32; kt++)
            m = fmaxf(m, fmaxf(fmaxf(acc[kt][0], acc[kt][1]),
                               fmaxf(acc[kt][2], acc[kt][3])));
        m = fmaxf(m, __shfl_xor(m, 16));
        m = fmaxf(m, __shfl_xor(m, 32));
        float s = 0.f;
        #pragma unroll
        for (int kt = 0; kt < 32; kt++) {
            acc[kt][0] = __expf(acc[kt][0] - m);
            acc[kt][1] = __expf(acc[kt][1] - m);
            acc[kt][2] = __expf(acc[kt][2] - m);
            acc[kt][3] = __expf(acc[kt][3] - m);
            s += acc[kt][0] + acc[kt][1] + acc[kt][2] + acc[kt][3];
        }
        s += __shfl_xor(s, 16);
        s += __shfl_xor(s, 32);
        float inv = 1.0f / s;

        // pack P (x inv) into f16 A-frags: pa[T] slots i: keys 4g+(i&3) of tiles 2T,2T+1
        half8_t pa[16];
        #pragma unroll
        for (int T = 0; T < 16; T++) {
            pa[T][0] = (f16)(acc[2 * T][0] * inv);
            pa[T][1] = (f16)(acc[2 * T][1] * inv);
            pa[T][2] = (f16)(acc[2 * T][2] * inv);
            pa[T][3] = (f16)(acc[2 * T][3] * inv);
            pa[T][4] = (f16)(acc[2 * T + 1][0] * inv);
            pa[T][5] = (f16)(acc[2 * T + 1][1] * inv);
            pa[T][6] = (f16)(acc[2 * T + 1][2] * inv);
            pa[T][7] = (f16)(acc[2 * T + 1][3] * inv);
        }

        // PV: O[q][hd], accumulate over 16 key-chunks of 32
        float4_t oa0 = {0.f, 0.f, 0.f, 0.f}, oa1 = {0.f, 0.f, 0.f, 0.f};
        #pragma unroll
        for (int T = 0; T < 16; T++) {
            int hd0 = q16;
            half4_t b00 = *(half4_t*)(VT + hd0 * 512 + (((8 * T + g + hd0) & 127) * 4));
            half4_t b01 = *(half4_t*)(VT + hd0 * 512 + (((8 * T + 4 + g + hd0) & 127) * 4));
            half8_t vb0;
            vb0[0] = b00[0]; vb0[1] = b00[1]; vb0[2] = b00[2]; vb0[3] = b00[3];
            vb0[4] = b01[0]; vb0[5] = b01[1]; vb0[6] = b01[2]; vb0[7] = b01[3];
            oa0 = __builtin_amdgcn_mfma_f32_16x16x32_f16(pa[T], vb0, oa0, 0, 0, 0);
            int hd1 = 16 + q16;
            half4_t b10 = *(half4_t*)(VT + hd1 * 512 + (((8 * T + g + hd1) & 127) * 4));
            half4_t b11 = *(half4_t*)(VT + hd1 * 512 + (((8 * T + 4 + g + hd1) & 127) * 4));
            half8_t vb1;
            vb1[0] = b10[0]; vb1[1] = b10[1]; vb1[2] = b10[2]; vb1[3] = b10[3];
            vb1[4] = b11[0]; vb1[5] = b11[1]; vb1[6] = b11[2]; vb1[7] = b11[3];
            oa1 = __builtin_amdgcn_mfma_f32_16x16x32_f16(pa[T], vb1, oa1, 0, 0, 0);
        }

        // write O: lane holds O[q = qt*16 + 4g + r][hd = q16 (+16)]
        #pragma unroll
        for (int r = 0; r < 4; r++) {
            size_t row = (size_t)(b * SNODES + qt * 16 + 4 * g + r);
            ao[row * CCH + hh * HDIM + q16]      = oa0[r];
            ao[row * CCH + hh * HDIM + 16 + q16] = oa1[r];
        }
    }
}

// ---------------- pooling + head ----------------
__global__ void k_pool(const float* __restrict__ h, const int* __restrict__ batch,
                       float* __restrict__ pooled) {
    int gid = blockIdx.x * blockDim.x + threadIdx.x;
    if (gid >= NNODES * 32) return;
    int n = gid >> 5, c4 = gid & 31;
    int g = batch[n];
    float4 v = ((const float4*)h)[gid];
    float* pp = pooled + (size_t)g * CCH + c4 * 4;
    atomicAdd(pp + 0, v.x);
    atomicAdd(pp + 1, v.y);
    atomicAdd(pp + 2, v.z);
    atomicAdd(pp + 3, v.w);
}

__global__ void k_cnt(const int* __restrict__ batch, float* __restrict__ cnt) {
    int n = blockIdx.x * blockDim.x + threadIdx.x;
    if (n < NNODES) atomicAdd(&cnt[batch[n]], 1.0f);
}

__global__ __launch_bounds__(256) void k_head(const float* __restrict__ pooled,
                                              const float* __restrict__ cnt,
                                              const float* __restrict__ Wh,
                                              const float* __restrict__ bh,
                                              const float* __restrict__ Wo,
                                              const float* __restrict__ bo,
                                              float* __restrict__ out) {
    __shared__ float p[128];
    __shared__ float red[256];
    int g = blockIdx.x, t = threadIdx.x;
    if (t < 128) p[t] = pooled[g * CCH + t] / cnt[g];
    __syncthreads();
    float a = bh[t];
    for (int k = 0; k < 128; k++) a = fmaf(p[k], Wh[k * HIDDEN + t], a);
    float z = gelu_f(a);
    red[t] = z * Wo[t];
    __syncthreads();
    for (int s = 128; s > 0; s >>= 1) {
        if (t < s) red[t] += red[t + s];
        __syncthreads();
    }
    if (t == 0) out[g] = red[0] + bo[0];
}

// ---------------- launch ----------------
extern "C" void kernel_launch(void* const* d_in, const int* in_sizes, int n_in,
                              void* d_out, int out_size, void* d_ws, size_t ws_size,
                              hipStream_t stream) {
    const float* x      = (const float*)d_in[0];
    const float* pe     = (const float*)d_in[1];
    const int*   ei     = (const int*)d_in[2];
    const int*   batch  = (const int*)d_in[3];
    const float* W_emb  = (const float*)d_in[4];
    const float* b_emb  = (const float*)d_in[5];
    const float* gcn_w  = (const float*)d_in[6];
    const float* gcn_b  = (const float*)d_in[7];
    const float* in_w   = (const float*)d_in[8];
    const float* in_b   = (const float*)d_in[9];
    const float* out_w  = (const float*)d_in[10];
    const float* out_b  = (const float*)d_in[11];
    const float* mlp_w1 = (const float*)d_in[12];
    const float* mlp_b1 = (const float*)d_in[13];
    const float* mlp_w2 = (const float*)d_in[14];
    const float* mlp_b2 = (const float*)d_in[15];
    const float* g1     = (const float*)d_in[16];
    const float* be1    = (const float*)d_in[17];
    const float* g2     = (const float*)d_in[18];
    const float* be2    = (const float*)d_in[19];
    const float* g3     = (const float*)d_in[20];
    const float* be3    = (const float*)d_in[21];
    const float* W_hid  = (const float*)d_in[22];
    const float* b_hid  = (const float*)d_in[23];
    const float* W_out  = (const float*)d_in[24];
    const float* b_out  = (const float*)d_in[25];
    float* out = (float*)d_out;

    float* ws = (float*)d_ws;
    const size_t NC = (size_t)NNODES * CCH;
    float* dinv   = ws;
    float* h      = dinv + NNODES;
    float* A      = h + NC;
    float* Bb     = A + NC;
    float* qkv    = Bb + NC;                          // N*384
    float* part   = qkv + (size_t)NNODES * 384;       // 128*256
    float* sc     = part + 128 * 256;
    float* sh     = sc + CCH;
    float* pooled = sh + CCH;                         // B*C
    float* cnt    = pooled + (size_t)NB_GRAPH * CCH;  // B
    int*   ideg   = (int*)(cnt + NB_GRAPH);           // N
    int*   rowptr = ideg + NNODES;                    // N+1
    int*   cursor = rowptr + NNODES + 1;              // N
    int*   col    = cursor + NNODES;                  // E

    const int* srcp = ei;
    const int* dstp = ei + NEDGES;

    const int NC4 = NNODES * 32;  // float4 count of an [N,C] buffer

    // ---- CSR build + dinv ----
    hipMemsetAsync(ideg, 0, NNODES * sizeof(int), stream);
    k_count<<<NEDGES / 256, 256, 0, stream>>>(dstp, ideg);
    k_dinv_from_deg<<<NNODES / 256, 256, 0, stream>>>(ideg, dinv);
    k_scan<<<1, 1024, 0, stream>>>(ideg, rowptr, cursor);
    k_fill_edges<<<NEDGES / 256, 256, 0, stream>>>(srcp, dstp, cursor, col);

    // embedding: h = [x|pe] @ W_emb + b_emb
    k_concat<<<(NNODES * 20) / 256, 256, 0, stream>>>(x, pe, qkv);
    k_gemm64<0, false><<<dim3(CCH / 64, NNODES / 64), 256, 0, stream>>>(
        qkv, W_emb, b_emb, nullptr, h, NNODES, CCH, INDIM);

    for (int l = 0; l < NLAYERS; l++) {
        // --- GCN branch: xws = (h @ W) * dinv (row-scaled in epilogue) ---
        k_gemm64<0, false><<<dim3(CCH / 64, NNODES / 64), 256, 0, stream>>>(
            h, gcn_w + (size_t)l * CCH * CCH, nullptr, dinv, A, NNODES, CCH, CCH);
        k_gcn_gather<<<NNODES / 8, 256, 0, stream>>>(
            rowptr, col, A, dinv, gcn_b + l * CCH, Bb);
        k_bn_stats<<<128, 256, 0, stream>>>(Bb, h, part);
        k_bn_finalize<<<1, 128, 0, stream>>>(part, g1 + l * CCH, be1 + l * CCH, sc, sh);
        k_bn_apply<0><<<NC4 / 256, 256, 0, stream>>>(Bb, h, sc, sh, A);  // h1 = A

        // --- attention branch ---
        k_gemm64<0, true><<<dim3(384 / 64, NNODES / 64), 256, 0, stream>>>(
            h, in_w + (size_t)l * 384 * CCH, in_b + l * 384, nullptr, qkv, NNODES, 384, CCH);
        k_attn_mfma<<<NB_GRAPH * NHEADS, 256, 0, stream>>>(qkv, Bb);  // ao = Bb
        k_gemm64<0, true><<<dim3(CCH / 64, NNODES / 64), 256, 0, stream>>>(
            Bb, out_w + (size_t)l * CCH * CCH, out_b + l * CCH, nullptr, qkv, NNODES, CCH, CCH);
        k_bn_stats<<<128, 256, 0, stream>>>(qkv, h, part);
        k_bn_finalize<<<1, 128, 0, stream>>>(part, g2 + l * CCH, be2 + l * CCH, sc, sh);
        k_bn_apply<0><<<NC4 / 256, 256, 0, stream>>>(qkv, h, sc, sh, Bb);  // h2 = Bb

        // --- combine + MLP ---
        k_add<<<NC4 / 256, 256, 0, stream>>>(A, Bb);  // out = h1 + h2 (in A)
        k_gemm64<1, false><<<dim3(256 / 64, NNODES / 64), 256, 0, stream>>>(
            A, mlp_w1 + (size_t)l * CCH * 256, mlp_b1 + l * 256, nullptr, qkv, NNODES, 256, CCH);
        k_gemm64<0, false><<<dim3(CCH / 64, NNODES / 64), 256, 0, stream>>>(
            qkv, mlp_w2 + (size_t)l * 256 * CCH, mlp_b2 + l * CCH, nullptr, Bb, NNODES, CCH, 256);
        k_bn_stats<<<128, 256, 0, stream>>>(A, Bb, part);
        k_bn_finalize<<<1, 128, 0, stream>>>(part, g3 + l * CCH, be3 + l * CCH, sc, sh);
        k_bn_apply<2><<<NC4 / 256, 256, 0, stream>>>(A, Bb, sc, sh, h);  // h = gelu(bn)
    }

    // pooling + head
    hipMemsetAsync(pooled, 0, ((size_t)NB_GRAPH * CCH + NB_GRAPH) * sizeof(float), stream);
    k_pool<<<NC4 / 256, 256, 0, stream>>>(h, batch, pooled);
    k_cnt<<<NNODES / 256, 256, 0, stream>>>(batch, cnt);
    k_head<<<NB_GRAPH, 256, 0, stream>>>(pooled, cnt, W_hid, b_hid, W_out, b_out, out);
}

// Round 5
// 1018.947 us; speedup vs baseline: 12.4518x; 1.3845x over previous
//
#include <hip/hip_runtime.h>
#include <hip/hip_bf16.h>
#include <math.h>

#define NNODES 32768
#define NEDGES 524288
#define CCH 128
#define NLAYERS 3
#define NHEADS 4
#define HDIM 32
#define NB_GRAPH 64
#define SNODES 512
#define INDIM 80
#define HIDDEN 256
#define BNEPS 1e-5f

typedef _Float16 f16;
typedef f16 half8_t __attribute__((ext_vector_type(8)));
typedef f16 half4_t __attribute__((ext_vector_type(4)));
typedef float float4_t __attribute__((ext_vector_type(4)));

__device__ __forceinline__ float gelu_f(float x) {
    return 0.5f * x * (1.0f + erff(x * 0.70710678118654752f));
}

// ---------------- CSR build ----------------
__global__ void k_count(const int* __restrict__ dst, int* __restrict__ deg) {
    int e = blockIdx.x * blockDim.x + threadIdx.x;
    if (e < NEDGES) atomicAdd(&deg[dst[e]], 1);
}

__global__ void k_dinv_from_deg(const int* __restrict__ deg, float* __restrict__ dinv) {
    int i = blockIdx.x * blockDim.x + threadIdx.x;
    if (i < NNODES) dinv[i] = rsqrtf((float)(deg[i] + 1));  // +1 self loop
}

__global__ __launch_bounds__(1024) void k_scan(const int* __restrict__ deg,
                                               int* __restrict__ rowptr,
                                               int* __restrict__ cursor) {
    __shared__ int sa[1024], sb[1024];
    int t = threadIdx.x;
    int base = t * 32;
    int local[32];
    int s = 0;
    #pragma unroll
    for (int i = 0; i < 32; i++) { local[i] = s; s += deg[base + i]; }
    sa[t] = s;
    __syncthreads();
    int* sp = sa; int* dp = sb;
    for (int off = 1; off < 1024; off <<= 1) {
        dp[t] = (t >= off) ? sp[t] + sp[t - off] : sp[t];
        __syncthreads();
        int* tmp = sp; sp = dp; dp = tmp;
    }
    int excl = (t == 0) ? 0 : sp[t - 1];
    #pragma unroll
    for (int i = 0; i < 32; i++) {
        int v = excl + local[i];
        rowptr[base + i] = v;
        cursor[base + i] = v;
    }
    if (t == 1023) rowptr[NNODES] = sp[1023];
}

__global__ void k_fill_edges(const int* __restrict__ src, const int* __restrict__ dst,
                             int* __restrict__ cursor, int* __restrict__ col) {
    int e = blockIdx.x * blockDim.x + threadIdx.x;
    if (e >= NEDGES) return;
    int pos = atomicAdd(&cursor[dst[e]], 1);
    col[pos] = src[e];
}

// ---------------- concat (padded to K=128) ----------------
__global__ void k_concat(const float* __restrict__ x, const float* __restrict__ pe,
                         float* __restrict__ out) {
    int gid = blockIdx.x * blockDim.x + threadIdx.x;
    if (gid >= NNODES * 32) return;
    int n = gid >> 5, q = gid & 31;
    float4 v = {0.f, 0.f, 0.f, 0.f};
    if (q < 16)      v = ((const float4*)x)[(size_t)n * 16 + q];
    else if (q < 20) v = ((const float4*)pe)[(size_t)n * 4 + (q - 16)];
    ((float4*)out)[gid] = v;
}

// ---------------- weight conversion: fp32 -> hi/lo f16, stored [N][Kp] ----------------
// trans=0: src is [Ks][N] (row-major); trans=1: src is [N][Ks]. k >= Ks zero-padded.
__global__ void k_wconv(const float* __restrict__ src, f16* __restrict__ hi,
                        f16* __restrict__ lo, int Nn, int Ks, int Kp, int trans, int L) {
    int gid = blockIdx.x * blockDim.x + threadIdx.x;
    int per = Nn * Kp;
    if (gid >= per * L) return;
    int l = gid / per, r = gid % per;
    int n = r / Kp, k = r % Kp;
    float v = 0.f;
    if (k < Ks)
        v = trans ? src[(size_t)l * Nn * Ks + (size_t)n * Ks + k]
                  : src[(size_t)l * Ks * Nn + (size_t)k * Nn + n];
    f16 h = (f16)v;
    hi[gid] = h;
    lo[gid] = (f16)(v - (float)h);
}

// ---------------- split-f16 MFMA GEMM ----------------
// C[M,N] = act((A[M,K] @ Wt^T + bias) * rowscale); Wt hi/lo are [N][K] f16.
// grid (N/128, M/128), 256 threads (4 waves). K % 32 == 0.
// 3 passes: hi*hi + lo*hi + hi*lo (error ~2^-22).
template<int ACT>
__global__ __launch_bounds__(256) void k_gemm_mfma(
        const float* __restrict__ A, const f16* __restrict__ Whi,
        const f16* __restrict__ Wlo, const float* __restrict__ bias,
        const float* __restrict__ rowscale, float* __restrict__ C,
        int M, int N, int K) {
    __shared__ f16 Ah[128 * 40];
    __shared__ f16 Al[128 * 40];
    __shared__ f16 Bh[128 * 40];
    __shared__ f16 Bl[128 * 40];
    const int t = threadIdx.x;
    const int bm = blockIdx.y * 128, bn = blockIdx.x * 128;
    const int w = t >> 6, lane = t & 63;
    const int g = lane >> 4, q = lane & 15;

    float4_t acc[2][8];
    #pragma unroll
    for (int mt = 0; mt < 2; mt++)
        #pragma unroll
        for (int nt = 0; nt < 8; nt++)
            acc[mt][nt] = (float4_t){0.f, 0.f, 0.f, 0.f};

    const int srow = t >> 1, shf = (t & 1) * 16;

    for (int kc = 0; kc < K; kc += 32) {
        // stage A (fp32 -> hi/lo f16)
        {
            const float* ap = A + (size_t)(bm + srow) * K + kc + shf;
            float va[16];
            *(float4*)&va[0]  = ((const float4*)ap)[0];
            *(float4*)&va[4]  = ((const float4*)ap)[1];
            *(float4*)&va[8]  = ((const float4*)ap)[2];
            *(float4*)&va[12] = ((const float4*)ap)[3];
            half8_t h0, h1, l0, l1;
            #pragma unroll
            for (int j = 0; j < 8; j++) {
                f16 h = (f16)va[j];
                h0[j] = h; l0[j] = (f16)(va[j] - (float)h);
            }
            #pragma unroll
            for (int j = 0; j < 8; j++) {
                f16 h = (f16)va[8 + j];
                h1[j] = h; l1[j] = (f16)(va[8 + j] - (float)h);
            }
            *(half8_t*)&Ah[srow * 40 + shf]     = h0;
            *(half8_t*)&Ah[srow * 40 + shf + 8] = h1;
            *(half8_t*)&Al[srow * 40 + shf]     = l0;
            *(half8_t*)&Al[srow * 40 + shf + 8] = l1;
        }
        // stage B (already f16)
        {
            const f16* bp = Whi + (size_t)(bn + srow) * K + kc + shf;
            *(half8_t*)&Bh[srow * 40 + shf]     = ((const half8_t*)bp)[0];
            *(half8_t*)&Bh[srow * 40 + shf + 8] = ((const half8_t*)bp)[1];
            const f16* lp = Wlo + (size_t)(bn + srow) * K + kc + shf;
            *(half8_t*)&Bl[srow * 40 + shf]     = ((const half8_t*)lp)[0];
            *(half8_t*)&Bl[srow * 40 + shf + 8] = ((const half8_t*)lp)[1];
        }
        __syncthreads();

        half8_t ah[2], al[2];
        #pragma unroll
        for (int mt = 0; mt < 2; mt++) {
            ah[mt] = *(half8_t*)&Ah[(w * 32 + mt * 16 + q) * 40 + g * 8];
            al[mt] = *(half8_t*)&Al[(w * 32 + mt * 16 + q) * 40 + g * 8];
        }
        #pragma unroll
        for (int nt = 0; nt < 8; nt++) {
            half8_t bh = *(half8_t*)&Bh[(nt * 16 + q) * 40 + g * 8];
            half8_t bl = *(half8_t*)&Bl[(nt * 16 + q) * 40 + g * 8];
            #pragma unroll
            for (int mt = 0; mt < 2; mt++) {
                acc[mt][nt] = __builtin_amdgcn_mfma_f32_16x16x32_f16(ah[mt], bh, acc[mt][nt], 0, 0, 0);
                acc[mt][nt] = __builtin_amdgcn_mfma_f32_16x16x32_f16(al[mt], bh, acc[mt][nt], 0, 0, 0);
                acc[mt][nt] = __builtin_amdgcn_mfma_f32_16x16x32_f16(ah[mt], bl, acc[mt][nt], 0, 0, 0);
            }
        }
        __syncthreads();
    }

    // epilogue: D[row=4g+r][col=q] per 16x16 tile
    #pragma unroll
    for (int mt = 0; mt < 2; mt++) {
        #pragma unroll
        for (int r = 0; r < 4; r++) {
            int row = bm + w * 32 + mt * 16 + 4 * g + r;
            float rs = rowscale ? rowscale[row] : 1.0f;
            #pragma unroll
            for (int nt = 0; nt < 8; nt++) {
                int cn = bn + nt * 16 + q;
                float v = acc[mt][nt][r] + (bias ? bias[cn] : 0.0f);
                v *= rs;
                if (ACT == 1) v = fmaxf(v, 0.0f);
                C[(size_t)row * N + cn] = v;
            }
        }
    }
}

// ---------------- GCN gather ----------------
__global__ __launch_bounds__(256) void k_gcn_gather(
        const int* __restrict__ rowptr, const int* __restrict__ col,
        const float* __restrict__ xws, const float* __restrict__ dinv,
        const float* __restrict__ bias, float* __restrict__ loc) {
    int t = threadIdx.x;
    int node = blockIdx.x * 8 + (t >> 5);
    int q = t & 31;
    int r0 = rowptr[node], r1 = rowptr[node + 1];
    float4 acc = ((const float4*)(xws + (size_t)node * CCH))[q];  // self loop
    for (int j = r0; j < r1; j++) {
        int s = col[j];
        float4 v = ((const float4*)(xws + (size_t)s * CCH))[q];
        acc.x += v.x; acc.y += v.y; acc.z += v.z; acc.w += v.w;
    }
    float dv = dinv[node];
    float4 b4 = ((const float4*)bias)[q];
    float4 o;
    o.x = fmaf(acc.x, dv, b4.x); o.y = fmaf(acc.y, dv, b4.y);
    o.z = fmaf(acc.z, dv, b4.z); o.w = fmaf(acc.w, dv, b4.w);
    ((float4*)(loc + (size_t)node * CCH))[q] = o;
}

// ---------------- BatchNorm ----------------
__global__ __launch_bounds__(256) void k_bn_stats(const float* __restrict__ a,
                                                  const float* __restrict__ b,
                                                  float* __restrict__ part) {
    __shared__ float s1[256], s2[256];
    int t = threadIdx.x, blk = blockIdx.x;
    int c = t & 127, half = t >> 7;
    float sum = 0.f, sq = 0.f;
    for (int i = 0; i < 128; i++) {
        size_t r = (size_t)blk * 256 + half + 2 * i;
        float v = a[r * CCH + c] + b[r * CCH + c];
        sum += v;
        sq = fmaf(v, v, sq);
    }
    s1[t] = sum; s2[t] = sq;
    __syncthreads();
    if (t < 128) {
        part[blk * 256 + t]       = s1[t] + s1[t + 128];
        part[blk * 256 + 128 + t] = s2[t] + s2[t + 128];
    }
}

__global__ void k_bn_finalize(const float* __restrict__ part, const float* __restrict__ g,
                              const float* __restrict__ be, float* __restrict__ sc,
                              float* __restrict__ sh) {
    int c = threadIdx.x;  // 128 threads
    float s = 0.f, sq = 0.f;
    for (int bk = 0; bk < 128; bk++) {
        s  += part[bk * 256 + c];
        sq += part[bk * 256 + 128 + c];
    }
    float mu = s / (float)NNODES;
    float var = sq / (float)NNODES - mu * mu;
    float rs = rsqrtf(var + BNEPS);
    float gg = g[c] * rs;
    sc[c] = gg;
    sh[c] = be[c] - mu * gg;
}

template<int ACT>
__global__ void k_bn_apply(const float* __restrict__ a, const float* __restrict__ b,
                           const float* __restrict__ sc, const float* __restrict__ sh,
                           float* __restrict__ out) {
    int gid = blockIdx.x * blockDim.x + threadIdx.x;
    if (gid >= NNODES * 32) return;
    int c = (gid & 31) * 4;
    float4 av = ((const float4*)a)[gid];
    float4 bv = ((const float4*)b)[gid];
    float r[4];
    float xs[4] = {av.x + bv.x, av.y + bv.y, av.z + bv.z, av.w + bv.w};
    #pragma unroll
    for (int j = 0; j < 4; j++) {
        float v = fmaf(xs[j], sc[c + j], sh[c + j]);
        if (ACT == 2) v = gelu_f(v);
        r[j] = v;
    }
    float4 o = {r[0], r[1], r[2], r[3]};
    ((float4*)out)[gid] = o;
}

__global__ void k_add(float* __restrict__ a, const float* __restrict__ b) {
    int gid = blockIdx.x * blockDim.x + threadIdx.x;
    if (gid >= NNODES * 32) return;
    float4 av = ((float4*)a)[gid];
    float4 bv = ((const float4*)b)[gid];
    av.x += bv.x; av.y += bv.y; av.z += bv.z; av.w += bv.w;
    ((float4*)a)[gid] = av;
}

// ---------------- MFMA attention ----------------
__global__ __launch_bounds__(256, 1) void k_attn_mfma(const float* __restrict__ qkv,
                                                      float* __restrict__ ao) {
    __shared__ f16 Ks[512 * 40];   // K rows padded to 40 f16 (80B)
    __shared__ f16 VT[32 * 512];   // V^T [hd][key], keys in 4-chunks rotated by hd
    const int bh = blockIdx.x;
    const int b = bh >> 2, hh = bh & 3;
    const int t = threadIdx.x;
    const int lane = t & 63, wave = t >> 6;
    const int g = lane >> 4, q16 = lane & 15;
    const float scale = 0.17677669529663689f;  // 1/sqrt(32)

    const float* base = qkv + (size_t)b * SNODES * 384;

    #pragma unroll
    for (int it = 0; it < 8; it++) {
        int u = it * 256 + t;
        int row = u >> 2, c = u & 3;
        const float* gp = base + (size_t)row * 384 + CCH + hh * HDIM + c * 8;
        float4 v0 = *(const float4*)gp;
        float4 v1 = *(const float4*)(gp + 4);
        half8_t hv;
        hv[0] = (f16)v0.x; hv[1] = (f16)v0.y; hv[2] = (f16)v0.z; hv[3] = (f16)v0.w;
        hv[4] = (f16)v1.x; hv[5] = (f16)v1.y; hv[6] = (f16)v1.z; hv[7] = (f16)v1.w;
        *(half8_t*)(Ks + row * 40 + c * 8) = hv;
    }

    #pragma unroll
    for (int it = 0; it < 16; it++) {
        int j4 = (t >> 3) & 3;
        int n  = it * 32 + ((t >> 5) & 7) * 4 + j4;
        int c  = t & 7;
        float4 v = *(const float4*)(base + (size_t)n * 384 + 2 * CCH + hh * HDIM + c * 4);
        float4 u1;
        u1.x = __shfl_xor(v.x, 8); u1.y = __shfl_xor(v.y, 8);
        u1.z = __shfl_xor(v.z, 8); u1.w = __shfl_xor(v.w, 8);
        float4 w;
        if ((t & 8) == 0) { w.x = v.x;  w.y = u1.x; w.z = v.z;  w.w = u1.z; }
        else              { w.x = u1.y; w.y = v.y;  w.z = u1.w; w.w = v.w;  }
        float4 u2;
        u2.x = __shfl_xor(w.x, 16); u2.y = __shfl_xor(w.y, 16);
        u2.z = __shfl_xor(w.z, 16); u2.w = __shfl_xor(w.w, 16);
        float4 o;
        if ((t & 16) == 0) { o.x = w.x;  o.y = w.y;  o.z = u2.x; o.w = u2.y; }
        else               { o.x = u2.z; o.y = u2.w; o.z = w.z;  o.w = w.w;  }
        int hd = c * 4 + j4;
        int n0 = it * 32 + ((t >> 5) & 7) * 4;
        half4_t pk;
        pk[0] = (f16)o.x; pk[1] = (f16)o.y; pk[2] = (f16)o.z; pk[3] = (f16)o.w;
        int pos = ((n0 >> 2) + hd) & 127;
        *(half4_t*)(VT + hd * 512 + pos * 4) = pk;
    }
    __syncthreads();

    for (int j = 0; j < 8; j++) {
        int qt = wave * 8 + j;

        const float* qp = base + (size_t)(qt * 16 + q16) * 384 + hh * HDIM + g * 8;
        float4 q0 = *(const float4*)qp;
        float4 q1 = *(const float4*)(qp + 4);
        half8_t qf;
        qf[0] = (f16)(q0.x * scale); qf[1] = (f16)(q0.y * scale);
        qf[2] = (f16)(q0.z * scale); qf[3] = (f16)(q0.w * scale);
        qf[4] = (f16)(q1.x * scale); qf[5] = (f16)(q1.y * scale);
        qf[6] = (f16)(q1.z * scale); qf[7] = (f16)(q1.w * scale);

        float4_t acc[32];
        #pragma unroll
        for (int kt = 0; kt < 32; kt++) {
            half8_t kf = *(half8_t*)(Ks + (kt * 16 + q16) * 40 + g * 8);
            float4_t z = {0.f, 0.f, 0.f, 0.f};
            acc[kt] = __builtin_amdgcn_mfma_f32_16x16x32_f16(kf, qf, z, 0, 0, 0);
        }

        float m = -1e30f;
        #pragma unroll
        for (int kt = 0; kt < 32; kt++)
            m = fmaxf(m, fmaxf(fmaxf(acc[kt][0], acc[kt][1]),
                               fmaxf(acc[kt][2], acc[kt][3])));
        m = fmaxf(m, __shfl_xor(m, 16));
        m = fmaxf(m, __shfl_xor(m, 32));
        float s = 0.f;
        #pragma unroll
        for (int kt = 0; kt < 32; kt++) {
            acc[kt][0] = __expf(acc[kt][0] - m);
            acc[kt][1] = __expf(acc[kt][1] - m);
            acc[kt][2] = __expf(acc[kt][2] - m);
            acc[kt][3] = __expf(acc[kt][3] - m);
            s += acc[kt][0] + acc[kt][1] + acc[kt][2] + acc[kt][3];
        }
        s += __shfl_xor(s, 16);
        s += __shfl_xor(s, 32);
        float inv = 1.0f / s;

        half8_t pa[16];
        #pragma unroll
        for (int T = 0; T < 16; T++) {
            pa[T][0] = (f16)(acc[2 * T][0] * inv);
            pa[T][1] = (f16)(acc[2 * T][1] * inv);
            pa[T][2] = (f16)(acc[2 * T][2] * inv);
            pa[T][3] = (f16)(acc[2 * T][3] * inv);
            pa[T][4] = (f16)(acc[2 * T + 1][0] * inv);
            pa[T][5] = (f16)(acc[2 * T + 1][1] * inv);
            pa[T][6] = (f16)(acc[2 * T + 1][2] * inv);
            pa[T][7] = (f16)(acc[2 * T + 1][3] * inv);
        }

        float4_t oa0 = {0.f, 0.f, 0.f, 0.f}, oa1 = {0.f, 0.f, 0.f, 0.f};
        #pragma unroll
        for (int T = 0; T < 16; T++) {
            int hd0 = q16;
            half4_t b00 = *(half4_t*)(VT + hd0 * 512 + (((8 * T + g + hd0) & 127) * 4));
            half4_t b01 = *(half4_t*)(VT + hd0 * 512 + (((8 * T + 4 + g + hd0) & 127) * 4));
            half8_t vb0;
            vb0[0] = b00[0]; vb0[1] = b00[1]; vb0[2] = b00[2]; vb0[3] = b00[3];
            vb0[4] = b01[0]; vb0[5] = b01[1]; vb0[6] = b01[2]; vb0[7] = b01[3];
            oa0 = __builtin_amdgcn_mfma_f32_16x16x32_f16(pa[T], vb0, oa0, 0, 0, 0);
            int hd1 = 16 + q16;
            half4_t b10 = *(half4_t*)(VT + hd1 * 512 + (((8 * T + g + hd1) & 127) * 4));
            half4_t b11 = *(half4_t*)(VT + hd1 * 512 + (((8 * T + 4 + g + hd1) & 127) * 4));
            half8_t vb1;
            vb1[0] = b10[0]; vb1[1] = b10[1]; vb1[2] = b10[2]; vb1[3] = b10[3];
            vb1[4] = b11[0]; vb1[5] = b11[1]; vb1[6] = b11[2]; vb1[7] = b11[3];
            oa1 = __builtin_amdgcn_mfma_f32_16x16x32_f16(pa[T], vb1, oa1, 0, 0, 0);
        }

        float inv1 = 1.0f;
        (void)inv1;
        #pragma unroll
        for (int r = 0; r < 4; r++) {
            size_t row = (size_t)(b * SNODES + qt * 16 + 4 * g + r);
            ao[row * CCH + hh * HDIM + q16]      = oa0[r];
            ao[row * CCH + hh * HDIM + 16 + q16] = oa1[r];
        }
    }
}

// ---------------- pooling (LDS-binned) + head ----------------
__global__ __launch_bounds__(256) void k_pool2(const float* __restrict__ h,
                                               const int* __restrict__ batch,
                                               float* __restrict__ pooled,
                                               float* __restrict__ cnt) {
    __shared__ float bins[NB_GRAPH * 132];
    __shared__ int cbin[NB_GRAPH];
    int t = threadIdx.x;
    for (int i = t; i < NB_GRAPH * 132; i += 256) bins[i] = 0.f;
    if (t < NB_GRAPH) cbin[t] = 0;
    __syncthreads();
    int n0 = blockIdx.x * 256;
    int c = t & 127, half = t >> 7;
    for (int i = 0; i < 128; i++) {
        int n = n0 + 2 * i + half;
        int g = batch[n];
        atomicAdd(&bins[g * 132 + c], h[(size_t)n * CCH + c]);
        if (c == 0) atomicAdd(&cbin[g], 1);
    }
    __syncthreads();
    for (int i = t; i < NB_GRAPH * CCH; i += 256) {
        int g = i >> 7, cc = i & 127;
        float v = bins[g * 132 + cc];
        if (v != 0.f) atomicAdd(&pooled[g * CCH + cc], v);
    }
    if (t < NB_GRAPH && cbin[t]) atomicAdd(&cnt[t], (float)cbin[t]);
}

__global__ __launch_bounds__(256) void k_head(const float* __restrict__ pooled,
                                              const float* __restrict__ cnt,
                                              const float* __restrict__ Wh,
                                              const float* __restrict__ bh,
                                              const float* __restrict__ Wo,
                                              const float* __restrict__ bo,
                                              float* __restrict__ out) {
    __shared__ float p[128];
    __shared__ float red[256];
    int g = blockIdx.x, t = threadIdx.x;
    if (t < 128) p[t] = pooled[g * CCH + t] / cnt[g];
    __syncthreads();
    float a = bh[t];
    for (int k = 0; k < 128; k++) a = fmaf(p[k], Wh[k * HIDDEN + t], a);
    float z = gelu_f(a);
    red[t] = z * Wo[t];
    __syncthreads();
    for (int s = 128; s > 0; s >>= 1) {
        if (t < s) red[t] += red[t + s];
        __syncthreads();
    }
    if (t == 0) out[g] = red[0] + bo[0];
}

// ---------------- launch ----------------
extern "C" void kernel_launch(void* const* d_in, const int* in_sizes, int n_in,
                              void* d_out, int out_size, void* d_ws, size_t ws_size,
                              hipStream_t stream) {
    const float* x      = (const float*)d_in[0];
    const float* pe     = (const float*)d_in[1];
    const int*   ei     = (const int*)d_in[2];
    const int*   batch  = (const int*)d_in[3];
    const float* W_emb  = (const float*)d_in[4];
    const float* b_emb  = (const float*)d_in[5];
    const float* gcn_w  = (const float*)d_in[6];
    const float* gcn_b  = (const float*)d_in[7];
    const float* in_w   = (const float*)d_in[8];
    const float* in_b   = (const float*)d_in[9];
    const float* out_w  = (const float*)d_in[10];
    const float* out_b  = (const float*)d_in[11];
    const float* mlp_w1 = (const float*)d_in[12];
    const float* mlp_b1 = (const float*)d_in[13];
    const float* mlp_w2 = (const float*)d_in[14];
    const float* mlp_b2 = (const float*)d_in[15];
    const float* g1     = (const float*)d_in[16];
    const float* be1    = (const float*)d_in[17];
    const float* g2     = (const float*)d_in[18];
    const float* be2    = (const float*)d_in[19];
    const float* g3     = (const float*)d_in[20];
    const float* be3    = (const float*)d_in[21];
    const float* W_hid  = (const float*)d_in[22];
    const float* b_hid  = (const float*)d_in[23];
    const float* W_out  = (const float*)d_in[24];
    const float* b_out  = (const float*)d_in[25];
    float* out = (float*)d_out;

    float* ws = (float*)d_ws;
    const size_t NC = (size_t)NNODES * CCH;
    float* dinv   = ws;
    float* h      = dinv + NNODES;
    float* A      = h + NC;
    float* Bb     = A + NC;
    float* qkv    = Bb + NC;                          // N*384
    float* part   = qkv + (size_t)NNODES * 384;       // 128*256
    float* sc     = part + 128 * 256;
    float* sh     = sc + CCH;
    float* pooled = sh + CCH;                         // B*C
    float* cnt    = pooled + (size_t)NB_GRAPH * CCH;  // B
    int*   ideg   = (int*)(cnt + NB_GRAPH);           // N
    int*   rowptr = ideg + NNODES;                    // N+1
    int*   cursor = rowptr + NNODES + 1;              // N
    int*   col    = cursor + NNODES;                  // E
    // f16 weight buffers (hi/lo), all stored [N][Kp]
    f16* wb    = (f16*)(col + NEDGES);
    f16* embh  = wb;                 f16* embl = embh + 128 * 128;
    f16* gcnh  = embl + 128 * 128;   f16* gcnl = gcnh + 3 * 128 * 128;
    f16* inh   = gcnl + 3 * 128 * 128;  f16* inl  = inh + 3 * 384 * 128;
    f16* outh  = inl + 3 * 384 * 128;   f16* outl = outh + 3 * 128 * 128;
    f16* m1h   = outl + 3 * 128 * 128;  f16* m1l  = m1h + 3 * 256 * 128;
    f16* m2h   = m1l + 3 * 256 * 128;   f16* m2l  = m2h + 3 * 128 * 256;

    const int* srcp = ei;
    const int* dstp = ei + NEDGES;

    const int NC4 = NNODES * 32;

    // ---- CSR build + dinv ----
    hipMemsetAsync(ideg, 0, NNODES * sizeof(int), stream);
    k_count<<<NEDGES / 256, 256, 0, stream>>>(dstp, ideg);
    k_dinv_from_deg<<<NNODES / 256, 256, 0, stream>>>(ideg, dinv);
    k_scan<<<1, 1024, 0, stream>>>(ideg, rowptr, cursor);
    k_fill_edges<<<NEDGES / 256, 256, 0, stream>>>(srcp, dstp, cursor, col);

    // ---- weight conversion ----
    k_wconv<<<(128 * 128 + 255) / 256, 256, 0, stream>>>(W_emb, embh, embl, 128, 80, 128, 0, 1);
    k_wconv<<<(3 * 128 * 128 + 255) / 256, 256, 0, stream>>>(gcn_w, gcnh, gcnl, 128, 128, 128, 0, 3);
    k_wconv<<<(3 * 384 * 128 + 255) / 256, 256, 0, stream>>>(in_w, inh, inl, 384, 128, 128, 1, 3);
    k_wconv<<<(3 * 128 * 128 + 255) / 256, 256, 0, stream>>>(out_w, outh, outl, 128, 128, 128, 1, 3);
    k_wconv<<<(3 * 256 * 128 + 255) / 256, 256, 0, stream>>>(mlp_w1, m1h, m1l, 256, 128, 128, 0, 3);
    k_wconv<<<(3 * 128 * 256 + 255) / 256, 256, 0, stream>>>(mlp_w2, m2h, m2l, 128, 256, 256, 0, 3);

    // embedding: h = [x|pe|0pad] @ W_emb + b_emb   (A buffer holds padded concat)
    k_concat<<<NC4 / 256, 256, 0, stream>>>(x, pe, A);
    k_gemm_mfma<0><<<dim3(1, NNODES / 128), 256, 0, stream>>>(
        A, embh, embl, b_emb, nullptr, h, NNODES, CCH, 128);

    for (int l = 0; l < NLAYERS; l++) {
        // --- GCN branch: xws = (h @ W) * dinv ---
        k_gemm_mfma<0><<<dim3(1, NNODES / 128), 256, 0, stream>>>(
            h, gcnh + (size_t)l * 128 * 128, gcnl + (size_t)l * 128 * 128,
            nullptr, dinv, A, NNODES, CCH, 128);
        k_gcn_gather<<<NNODES / 8, 256, 0, stream>>>(
            rowptr, col, A, dinv, gcn_b + l * CCH, Bb);
        k_bn_stats<<<128, 256, 0, stream>>>(Bb, h, part);
        k_bn_finalize<<<1, 128, 0, stream>>>(part, g1 + l * CCH, be1 + l * CCH, sc, sh);
        k_bn_apply<0><<<NC4 / 256, 256, 0, stream>>>(Bb, h, sc, sh, A);  // h1 = A

        // --- attention branch ---
        k_gemm_mfma<0><<<dim3(3, NNODES / 128), 256, 0, stream>>>(
            h, inh + (size_t)l * 384 * 128, inl + (size_t)l * 384 * 128,
            in_b + l * 384, nullptr, qkv, NNODES, 384, 128);
        k_attn_mfma<<<NB_GRAPH * NHEADS, 256, 0, stream>>>(qkv, Bb);  // ao = Bb
        k_gemm_mfma<0><<<dim3(1, NNODES / 128), 256, 0, stream>>>(
            Bb, outh + (size_t)l * 128 * 128, outl + (size_t)l * 128 * 128,
            out_b + l * CCH, nullptr, qkv, NNODES, CCH, 128);
        k_bn_stats<<<128, 256, 0, stream>>>(qkv, h, part);
        k_bn_finalize<<<1, 128, 0, stream>>>(part, g2 + l * CCH, be2 + l * CCH, sc, sh);
        k_bn_apply<0><<<NC4 / 256, 256, 0, stream>>>(qkv, h, sc, sh, Bb);  // h2 = Bb

        // --- combine + MLP ---
        k_add<<<NC4 / 256, 256, 0, stream>>>(A, Bb);  // out = h1 + h2 (in A)
        k_gemm_mfma<1><<<dim3(2, NNODES / 128), 256, 0, stream>>>(
            A, m1h + (size_t)l * 256 * 128, m1l + (size_t)l * 256 * 128,
            mlp_b1 + l * 256, nullptr, qkv, NNODES, 256, 128);
        k_gemm_mfma<0><<<dim3(1, NNODES / 128), 256, 0, stream>>>(
            qkv, m2h + (size_t)l * 128 * 256, m2l + (size_t)l * 128 * 256,
            mlp_b2 + l * CCH, nullptr, Bb, NNODES, CCH, 256);
        k_bn_stats<<<128, 256, 0, stream>>>(A, Bb, part);
        k_bn_finalize<<<1, 128, 0, stream>>>(part, g3 + l * CCH, be3 + l * CCH, sc, sh);
        k_bn_apply<2><<<NC4 / 256, 256, 0, stream>>>(A, Bb, sc, sh, h);  // h = gelu(bn)
    }

    // pooling + head
    hipMemsetAsync(pooled, 0, ((size_t)NB_GRAPH * CCH + NB_GRAPH) * sizeof(float), stream);
    k_pool2<<<NNODES / 256, 256, 0, stream>>>(h, batch, pooled, cnt);
    k_head<<<NB_GRAPH, 256, 0, stream>>>(pooled, cnt, W_hid, b_hid, W_out, b_out, out);
}